// Round 14
// baseline (6230.742 us; speedup 1.0000x reference)
//
#include <hip/hip_runtime.h>
#include <hip/hip_bf16.h>
#include <math.h>

#define N_NODES  50000
#define N_EDGES  800000
#define E_TOT    850000   /* edges + self loops */
#define N_GRAPHS 64
#define N_LOCS   50

typedef __hip_bfloat16 bf16;

// ---------------- static scratch ----------------
__device__ int      g_dt[20];                    // float inputs: 0=bf16, 1=f32, 2=f64
__device__ int      g_iw;                        // int inputs: 1 = int64, 0 = int32
__device__ float    g_T[(size_t)N_NODES * 129];  // transformed features (this layer)
__device__ float    g_H[(size_t)N_NODES * 129];  // layer output (next layer input)
__device__ float    g_O[(size_t)N_NODES * 129];  // scatter accumulator
__device__ float    g_es[N_NODES * 3];
__device__ float    g_ed[N_NODES * 3];
__device__ unsigned g_mkey[N_NODES * 3];         // segment-max keys
__device__ float    g_m[N_NODES * 3];            // segment max (finite, 0 if empty)
__device__ float    g_z[N_NODES * 3];            // exp-sum
__device__ float    g_alpha[(size_t)E_TOT * 3];  // unnormalized exp weights per edge/head
__device__ float    g_gsum[N_GRAPHS * 128];
__device__ float    g_gcnt[N_GRAPHS];

// ---------------- helpers ----------------
__device__ __forceinline__ float b2f(bf16 x){ return __bfloat162float(x); }
__device__ __forceinline__ float lrelu(float x){ return x > 0.f ? x : 0.2f * x; }
__device__ __forceinline__ int   clampi(int v, int lo, int hi){ return v < lo ? lo : (v > hi ? hi : v); }
__device__ __forceinline__ float finz(float v){
    unsigned u = __float_as_uint(v);
    return ((u & 0x7F800000u) == 0x7F800000u) ? 0.f : v;   // NaN/inf -> 0
}
// dtype-dispatching sanitized float input load: 0=bf16, 1=f32, 2=f64
__device__ __forceinline__ float ldin(const void* p, int m, size_t i){
    float v = (m == 2) ? (float)((const double*)p)[i]
            : (m == 1) ? ((const float*)p)[i]
            :            b2f(((const bf16*)p)[i]);
    return finz(v);
}
__device__ __forceinline__ int ldi(const void* p, int wide, size_t i){
    return wide ? (int)((const long long*)p)[i] : ((const int*)p)[i];
}
__device__ __forceinline__ float expc(float a){ return __expf(fminf(fmaxf(a, -80.f), 0.f)); }
// order-preserving float<->unsigned key (0 reserved as "empty" sentinel)
__device__ __forceinline__ unsigned fkey(float f){
    unsigned u = __float_as_uint(f);
    return (u & 0x80000000u) ? ~u : (u | 0x80000000u);
}
__device__ __forceinline__ float kinv(unsigned k){
    return __uint_as_float((k & 0x80000000u) ? (k ^ 0x80000000u) : ~k);
}
// edge -> (src,dst) including self-loops
__device__ __forceinline__ void edge_sd(const void* ei, int wide, int e, int& src, int& dst){
    if (e < N_EDGES){
        src = clampi(ldi(ei, wide, e), 0, N_NODES - 1);
        dst = clampi(ldi(ei, wide, (size_t)N_EDGES + e), 0, N_NODES - 1);
    } else {
        src = dst = e - N_EDGES;
    }
}

// ---------------- dtype detection (1 wave) ----------------
__global__ void k_detect(const void* x, const void* loc, const void* W0,
                         const void* as0, const void* ad0, const void* W1,
                         const void* as1, const void* ad1, const void* W2,
                         const void* as2, const void* ad2, const void* Wl1,
                         const void* Wl2, const void* ei){
    const void* ps[13] = {x, loc, W0, as0, ad0, W1, as1, ad1, W2, as2, ad2, Wl1, Wl2};
    const int  sl[13]  = {0,  1,   4,  5,   6,   8,  9,   10,  12, 13,  14,  16,  18};
    int lane = threadIdx.x;   // 64 lanes
    for (int t = 0; t < 13; t++){
        float vf = ((const float*)ps[t])[lane];
        unsigned uf = __float_as_uint(vf);
        bool hit64 = ((uf & 0x7F800000u) == 0x7F800000u) || fabsf(vf) > 1e4f;
        int n64 = __popcll(__ballot(hit64));

        float vb = b2f(((const bf16*)ps[t])[lane]);
        unsigned ub = __float_as_uint(vb);
        bool hit32 = ((ub & 0x7F800000u) == 0x7F800000u) || fabsf(vb) > 1e4f;
        int n32 = __popcll(__ballot(hit32));

        if (lane == 0) g_dt[sl[t]] = (n64 >= 2) ? 2 : ((n32 >= 2) ? 1 : 0);
    }
    int w0 = ((const int*)ei)[lane];
    unsigned long long zm = __ballot((lane & 1) && (w0 == 0));
    if (lane == 0){
        g_iw = (__popcll(zm) >= 16) ? 1 : 0;
        g_dt[2] = g_dt[3] = 0;
        g_dt[7] = g_dt[11] = g_dt[15] = 0;
        g_dt[17] = g_dt[19] = 0;
    }
}

// ---------------- zero init ----------------
__global__ void k_zero_global(){
    int i = blockIdx.x * blockDim.x + threadIdx.x;
    if (i < N_GRAPHS * 128) g_gsum[i] = 0.f;
    if (i < N_GRAPHS) g_gcnt[i] = 0.f;
}
template<int H, int C>
__global__ void k_zero_layer(){
    int i = blockIdx.x * blockDim.x + threadIdx.x;
    if (i < N_NODES * C) g_O[i] = 0.f;
    if (i < N_NODES * H){ g_mkey[i] = 0u; g_z[i] = 0.f; }
}

// ---------------- GEMMs ----------------
__global__ void k_gemm0(const void* __restrict__ x, const void* __restrict__ W){
    int dtx = g_dt[0], dtw = g_dt[4];
    int idx = blockIdx.x * blockDim.x + threadIdx.x;
    if (idx >= N_NODES * 129) return;
    int n = idx / 129, c = idx - n * 129;
    float acc = 0.f;
    #pragma unroll
    for (int k = 0; k < 6; k++)
        acc += ldin(x, dtx, (size_t)n * 6 + k) * ldin(W, dtw, k * 129 + c);
    g_T[idx] = finz(acc);
}

template<int K, int CO>
__global__ void k_gemm(const void* __restrict__ W, int slot){
    int dtw = g_dt[slot];
    int idx = blockIdx.x * blockDim.x + threadIdx.x;
    if (idx >= N_NODES * CO) return;
    int n = idx / CO, c = idx - n * CO;
    const float* ar = g_H + (size_t)n * K;
    float acc = 0.f;
    #pragma unroll 4
    for (int k = 0; k < K; k++) acc += finz(ar[k]) * ldin(W, dtw, k * CO + c);
    g_T[(size_t)n * CO + c] = finz(acc);
}

// ---------------- per-node attention coefficients ----------------
template<int H, int O, int C>
__global__ void k_esed(const void* __restrict__ as, const void* __restrict__ ad,
                       int slot_as, int slot_ad){
    int dta = g_dt[slot_as], dtd = g_dt[slot_ad];
    int idx = blockIdx.x * blockDim.x + threadIdx.x;
    if (idx >= N_NODES * H) return;
    int n = idx / H, h = idx - n * H;
    const float* tr = g_T + (size_t)n * C + h * O;
    float a = 0.f, b = 0.f;
    #pragma unroll 4
    for (int o = 0; o < O; o++){
        float v = finz(tr[o]);
        a += v * ldin(as, dta, h * O + o);
        b += v * ldin(ad, dtd, h * O + o);
    }
    g_es[idx] = finz(a); g_ed[idx] = finz(b);
}

// ---------------- edge-parallel attention (atomic-based) ----------
template<int H>
__global__ void k_emax(const void* __restrict__ ei){
    int wide = g_iw;
    int e = blockIdx.x * blockDim.x + threadIdx.x;
    if (e >= E_TOT) return;
    int src, dst; edge_sd(ei, wide, e, src, dst);
    #pragma unroll
    for (int h = 0; h < H; h++){
        float val = lrelu(finz(g_es[src * H + h]) + finz(g_ed[dst * H + h]));
        atomicMax(&g_mkey[dst * H + h], fkey(val));
    }
}

template<int H>
__global__ void k_mfin(){
    int idx = blockIdx.x * blockDim.x + threadIdx.x;
    if (idx >= N_NODES * H) return;
    unsigned k = g_mkey[idx];
    g_m[idx] = (k == 0u) ? 0.f : finz(kinv(k));
}

template<int H>
__global__ void k_esum(const void* __restrict__ ei){
    int wide = g_iw;
    int e = blockIdx.x * blockDim.x + threadIdx.x;
    if (e >= E_TOT) return;
    int src, dst; edge_sd(ei, wide, e, src, dst);
    #pragma unroll
    for (int h = 0; h < H; h++){
        float val = lrelu(finz(g_es[src * H + h]) + finz(g_ed[dst * H + h]));
        float w = expc(val - g_m[dst * H + h]);
        g_alpha[(size_t)e * H + h] = w;
        atomicAdd(&g_z[dst * H + h], w);
    }
}

template<int H, int O, int C>
__global__ void k_scatter(const void* __restrict__ ei){
    int wide = g_iw;
    int idx = blockIdx.x * blockDim.x + threadIdx.x;
    if (idx >= E_TOT * C) return;
    int e = idx / C, c = idx - e * C;
    int src, dst; edge_sd(ei, wide, e, src, dst);
    int h = c / O;
    float a = g_alpha[(size_t)e * H + h] / (g_z[dst * H + h] + 1e-16f);
    float v = finz(g_T[(size_t)src * C + c]) * a;
    atomicAdd(&g_O[(size_t)dst * C + c], v);
}

template<int C, bool LEAKY>
__global__ void k_bias(const void* __restrict__ bias, int slot_b){
    int dtb = g_dt[slot_b];
    int idx = blockIdx.x * blockDim.x + threadIdx.x;
    if (idx >= N_NODES * C) return;
    int c = idx % C;
    float o = finz(g_O[idx]) + ldin(bias, dtb, c);
    if (LEAKY) o = lrelu(o);
    g_H[idx] = finz(o);
}

// ---------------- pooling ----------------
__global__ void k_poolA(const void* __restrict__ batch){
    int wide = g_iw;
    int idx = blockIdx.x * blockDim.x + threadIdx.x;
    if (idx >= N_NODES * 128) return;
    int n = idx >> 7, c = idx & 127;
    int b = clampi(ldi(batch, wide, n), 0, N_GRAPHS - 1);
    atomicAdd(&g_gsum[b * 128 + c], finz(g_H[(size_t)n * 128 + c]));
}

__global__ void k_poolB(const void* __restrict__ batch){
    int wide = g_iw;
    int n = blockIdx.x * blockDim.x + threadIdx.x;
    if (n >= N_NODES) return;
    int b = clampi(ldi(batch, wide, n), 0, N_GRAPHS - 1);
    atomicAdd(&g_gcnt[b], 1.f);
}

// ---- OUTPUT IS FLOAT32 (r13 oracle: even-index bf16 writes invisible => harness reads f32)
__global__ void k_fin(float* __restrict__ out){
    int idx = blockIdx.x * blockDim.x + threadIdx.x;
    if (idx >= N_GRAPHS * 128) return;
    int b = idx >> 7, c = idx & 127;
    out[b * 256 + c] = finz(finz(g_gsum[idx]) / fmaxf(g_gcnt[b], 1.f));
}

// ---------------- location-encoder MLP (f32 output) ----------------
__global__ void k_loc2(const void* __restrict__ loc, const void* __restrict__ Wl1,
                       const void* __restrict__ bl1, const void* __restrict__ Wl2,
                       const void* __restrict__ bl2, float* __restrict__ out){
    int dtl = g_dt[1], dtw1 = g_dt[16], dtb1 = g_dt[17], dtw2 = g_dt[18], dtb2 = g_dt[19];
    int b = blockIdx.x;       // 64 blocks
    int t = threadIdx.x;      // 128 threads = output channels
    double acc = 0.0;
    for (int j = 0; j < 256; j++){
        float wj0 = ldin(Wl1, dtw1, j);
        float wj1 = ldin(Wl1, dtw1, 256 + j);
        float bj  = ldin(bl1, dtb1, j);
        double s = 0.0;
        for (int l = 0; l < N_LOCS; l++){
            float x0 = ldin(loc, dtl, ((size_t)b * N_LOCS + l) * 2);
            float x1 = ldin(loc, dtl, ((size_t)b * N_LOCS + l) * 2 + 1);
            s += (double)tanhf(x0 * wj0 + x1 * wj1 + bj);
        }
        acc += s * (double)ldin(Wl2, dtw2, (size_t)j * 128 + t);
    }
    float r = (float)(acc / (double)N_LOCS) + ldin(bl2, dtb2, t);
    out[(size_t)b * 256 + 128 + t] = finz(r);
}

// ---------------- per-layer driver ----------------
template<int H, int O, int C, bool LEAKY>
static void gat_layer(const void* ei, const void* as, const void* ad, const void* bias,
                      int s_as, int s_ad, int s_b, hipStream_t stream){
    const int EB  = (E_TOT + 255) / 256;
    const int NC  = (N_NODES * C + 255) / 256;
    const int NH  = (N_NODES * H + 255) / 256;
    const int EC  = (int)(((long long)E_TOT * C + 255) / 256);
    k_esed<H, O, C><<<NH, 256, 0, stream>>>(as, ad, s_as, s_ad);
    k_zero_layer<H, C><<<NC, 256, 0, stream>>>();
    k_emax<H><<<EB, 256, 0, stream>>>(ei);
    k_mfin<H><<<NH, 256, 0, stream>>>();
    k_esum<H><<<EB, 256, 0, stream>>>(ei);
    k_scatter<H, O, C><<<EC, 256, 0, stream>>>(ei);
    k_bias<C, LEAKY><<<NC, 256, 0, stream>>>(bias, s_b);
}

// ---------------- launch ----------------
extern "C" void kernel_launch(void* const* d_in, const int* in_sizes, int n_in,
                              void* d_out, int out_size, void* d_ws, size_t ws_size,
                              hipStream_t stream){
    static const int want[20] = {300000, 6400, 1600000, 50000,
                                 774, 129, 129, 129,
                                 16641, 129, 129, 129,
                                 16512, 128, 128, 128,
                                 512, 256, 32768, 128};
    const void* P[20];
    bool assigned[20];
    for (int s = 0; s < 20; s++){ P[s] = nullptr; assigned[s] = false; }
    bool ok = (n_in == 20);
    if (ok){
        for (int i = 0; i < 20; i++){
            int sz = in_sizes[i], hit = -1;
            for (int s = 0; s < 20; s++)
                if (!assigned[s] && want[s] == sz){ hit = s; break; }
            if (hit < 0){ ok = false; break; }
            P[hit] = d_in[i]; assigned[hit] = true;
        }
        for (int s = 0; s < 20 && ok; s++) if (!assigned[s]) ok = false;
    }
    if (!ok) for (int s = 0; s < 20 && s < n_in; s++) P[s] = d_in[s];

    const void* x    = P[0];
    const void* loc  = P[1];
    const void* ei   = P[2];
    const void* batch= P[3];
    const void* W0   = P[4];
    const void* as0  = P[5];
    const void* ad0  = P[6];
    const void* b0   = P[7];
    const void* W1   = P[8];
    const void* as1  = P[9];
    const void* ad1  = P[10];
    const void* b1   = P[11];
    const void* W2   = P[12];
    const void* as2  = P[13];
    const void* ad2  = P[14];
    const void* b2   = P[15];
    const void* Wl1  = P[16];
    const void* bl1  = P[17];
    const void* Wl2  = P[18];
    const void* bl2  = P[19];
    float* out = (float*)d_out;
    (void)d_ws; (void)ws_size; (void)out_size;

    k_detect<<<1, 64, 0, stream>>>(x, loc, W0, as0, ad0, W1, as1, ad1, W2, as2, ad2, Wl1, Wl2, ei);
    k_zero_global<<<(N_GRAPHS * 128 + 255) / 256, 256, 0, stream>>>();

    // layer 0
    k_gemm0<<<(N_NODES * 129 + 255) / 256, 256, 0, stream>>>(x, W0);
    gat_layer<3, 43, 129, true>(ei, as0, ad0, b0, 5, 6, 7, stream);

    // layer 1
    k_gemm<129, 129><<<(N_NODES * 129 + 255) / 256, 256, 0, stream>>>(W1, 8);
    gat_layer<3, 43, 129, true>(ei, as1, ad1, b1, 9, 10, 11, stream);

    // layer 2
    k_gemm<129, 128><<<(N_NODES * 128 + 255) / 256, 256, 0, stream>>>(W2, 12);
    gat_layer<1, 128, 128, false>(ei, as2, ad2, b2, 13, 14, 15, stream);

    // pooling + output (f32 stores)
    k_poolA<<<(N_NODES * 128 + 255) / 256, 256, 0, stream>>>(batch);
    k_poolB<<<(N_NODES + 255) / 256, 256, 0, stream>>>(batch);
    k_fin  <<<(N_GRAPHS * 128 + 255) / 256, 256, 0, stream>>>(out);
    k_loc2 <<<N_GRAPHS, 128, 0, stream>>>(loc, Wl1, bl1, Wl2, bl2, out);
}

// Round 15
// 3212.807 us; speedup vs baseline: 1.9393x; 1.9393x over previous
//
#include <hip/hip_runtime.h>
#include <hip/hip_bf16.h>
#include <math.h>

#define N_NODES  50000
#define N_EDGES  800000
#define E_TOT    850000   /* edges + self loops */
#define N_GRAPHS 64
#define N_LOCS   50

typedef __hip_bfloat16 bf16;

// ---------------- static scratch ----------------
__device__ int      g_dt[20];                    // float inputs: 0=bf16, 1=f32, 2=f64
__device__ int      g_iw;                        // int inputs: 1 = int64, 0 = int32
__device__ float    g_T[(size_t)N_NODES * 129];  // transformed features (this layer)
__device__ float    g_H[(size_t)N_NODES * 129];  // layer output (next layer input)
__device__ float    g_O[(size_t)N_NODES * 129];  // scatter accumulator
__device__ float    g_es[N_NODES * 3];
__device__ float    g_ed[N_NODES * 3];
__device__ unsigned g_mkey[N_NODES * 3];         // segment-max keys
__device__ float    g_m[N_NODES * 3];            // segment max (finite, 0 if empty)
__device__ float    g_z[N_NODES * 3];            // exp-sum
__device__ float    g_alpha[(size_t)E_TOT * 3];  // unnormalized exp weights per edge/head
__device__ float    g_gsum[N_GRAPHS * 128];
__device__ float    g_gcnt[N_GRAPHS];

// ---------------- helpers ----------------
__device__ __forceinline__ float b2f(bf16 x){ return __bfloat162float(x); }
__device__ __forceinline__ float lrelu(float x){ return x > 0.f ? x : 0.2f * x; }
__device__ __forceinline__ int   clampi(int v, int lo, int hi){ return v < lo ? lo : (v > hi ? hi : v); }
__device__ __forceinline__ float finz(float v){
    unsigned u = __float_as_uint(v);
    return ((u & 0x7F800000u) == 0x7F800000u) ? 0.f : v;   // NaN/inf -> 0
}
// dtype-dispatching sanitized float input load: 0=bf16, 1=f32, 2=f64
__device__ __forceinline__ float ldin(const void* p, int m, size_t i){
    float v = (m == 2) ? (float)((const double*)p)[i]
            : (m == 1) ? ((const float*)p)[i]
            :            b2f(((const bf16*)p)[i]);
    return finz(v);
}
__device__ __forceinline__ int ldi(const void* p, int wide, size_t i){
    return wide ? (int)((const long long*)p)[i] : ((const int*)p)[i];
}
__device__ __forceinline__ float expc(float a){ return __expf(fminf(fmaxf(a, -80.f), 0.f)); }
// order-preserving float<->unsigned key (0 reserved as "empty" sentinel)
__device__ __forceinline__ unsigned fkey(float f){
    unsigned u = __float_as_uint(f);
    return (u & 0x80000000u) ? ~u : (u | 0x80000000u);
}
__device__ __forceinline__ float kinv(unsigned k){
    return __uint_as_float((k & 0x80000000u) ? (k ^ 0x80000000u) : ~k);
}
// edge -> (src,dst) including self-loops
__device__ __forceinline__ void edge_sd(const void* ei, int wide, int e, int& src, int& dst){
    if (e < N_EDGES){
        src = clampi(ldi(ei, wide, e), 0, N_NODES - 1);
        dst = clampi(ldi(ei, wide, (size_t)N_EDGES + e), 0, N_NODES - 1);
    } else {
        src = dst = e - N_EDGES;
    }
}

// ---------------- dtype detection (1 wave) ----------------
__global__ void k_detect(const void* x, const void* loc, const void* W0,
                         const void* as0, const void* ad0, const void* W1,
                         const void* as1, const void* ad1, const void* W2,
                         const void* as2, const void* ad2, const void* Wl1,
                         const void* Wl2, const void* ei){
    const void* ps[13] = {x, loc, W0, as0, ad0, W1, as1, ad1, W2, as2, ad2, Wl1, Wl2};
    const int  sl[13]  = {0,  1,   4,  5,   6,   8,  9,   10,  12, 13,  14,  16,  18};
    int lane = threadIdx.x;   // 64 lanes
    for (int t = 0; t < 13; t++){
        float vf = ((const float*)ps[t])[lane];
        unsigned uf = __float_as_uint(vf);
        bool hit64 = ((uf & 0x7F800000u) == 0x7F800000u) || fabsf(vf) > 1e4f;
        int n64 = __popcll(__ballot(hit64));

        float vb = b2f(((const bf16*)ps[t])[lane]);
        unsigned ub = __float_as_uint(vb);
        bool hit32 = ((ub & 0x7F800000u) == 0x7F800000u) || fabsf(vb) > 1e4f;
        int n32 = __popcll(__ballot(hit32));

        if (lane == 0) g_dt[sl[t]] = (n64 >= 2) ? 2 : ((n32 >= 2) ? 1 : 0);
    }
    int w0 = ((const int*)ei)[lane];
    unsigned long long zm = __ballot((lane & 1) && (w0 == 0));
    if (lane == 0){
        g_iw = (__popcll(zm) >= 16) ? 1 : 0;
        g_dt[2] = g_dt[3] = 0;
        g_dt[7] = g_dt[11] = g_dt[15] = 0;
        g_dt[17] = g_dt[19] = 0;
    }
}

// ---------------- zero init ----------------
__global__ void k_zero_global(){
    int i = blockIdx.x * blockDim.x + threadIdx.x;
    if (i < N_GRAPHS * 128) g_gsum[i] = 0.f;
    if (i < N_GRAPHS) g_gcnt[i] = 0.f;
}
template<int H, int C>
__global__ void k_zero_layer(){
    int i = blockIdx.x * blockDim.x + threadIdx.x;
    if (i < N_NODES * C) g_O[i] = 0.f;
    if (i < N_NODES * H){ g_mkey[i] = 0u; g_z[i] = 0.f; }
}

// ---------------- GEMMs ----------------
__global__ void k_gemm0(const void* __restrict__ x, const void* __restrict__ W){
    int dtx = g_dt[0], dtw = g_dt[4];
    int idx = blockIdx.x * blockDim.x + threadIdx.x;
    if (idx >= N_NODES * 129) return;
    int n = idx / 129, c = idx - n * 129;
    float acc = 0.f;
    #pragma unroll
    for (int k = 0; k < 6; k++)
        acc += ldin(x, dtx, (size_t)n * 6 + k) * ldin(W, dtw, k * 129 + c);
    g_T[idx] = finz(acc);
}

template<int K, int CO>
__global__ void k_gemm(const void* __restrict__ W, int slot){
    int dtw = g_dt[slot];
    int idx = blockIdx.x * blockDim.x + threadIdx.x;
    if (idx >= N_NODES * CO) return;
    int n = idx / CO, c = idx - n * CO;
    const float* ar = g_H + (size_t)n * K;
    float acc = 0.f;
    #pragma unroll 4
    for (int k = 0; k < K; k++) acc += finz(ar[k]) * ldin(W, dtw, k * CO + c);
    g_T[(size_t)n * CO + c] = finz(acc);
}

// ---------------- per-node attention coefficients ----------------
template<int H, int O, int C>
__global__ void k_esed(const void* __restrict__ as, const void* __restrict__ ad,
                       int slot_as, int slot_ad){
    int dta = g_dt[slot_as], dtd = g_dt[slot_ad];
    int idx = blockIdx.x * blockDim.x + threadIdx.x;
    if (idx >= N_NODES * H) return;
    int n = idx / H, h = idx - n * H;
    const float* tr = g_T + (size_t)n * C + h * O;
    float a = 0.f, b = 0.f;
    #pragma unroll 4
    for (int o = 0; o < O; o++){
        float v = finz(tr[o]);
        a += v * ldin(as, dta, h * O + o);
        b += v * ldin(ad, dtd, h * O + o);
    }
    g_es[idx] = finz(a); g_ed[idx] = finz(b);
}

// ---------------- edge-parallel attention (atomic-based) ----------
template<int H>
__global__ void k_emax(const void* __restrict__ ei){
    int wide = g_iw;
    int e = blockIdx.x * blockDim.x + threadIdx.x;
    if (e >= E_TOT) return;
    int src, dst; edge_sd(ei, wide, e, src, dst);
    #pragma unroll
    for (int h = 0; h < H; h++){
        float val = lrelu(finz(g_es[src * H + h]) + finz(g_ed[dst * H + h]));
        atomicMax(&g_mkey[dst * H + h], fkey(val));
    }
}

template<int H>
__global__ void k_mfin(){
    int idx = blockIdx.x * blockDim.x + threadIdx.x;
    if (idx >= N_NODES * H) return;
    unsigned k = g_mkey[idx];
    g_m[idx] = (k == 0u) ? 0.f : finz(kinv(k));
}

template<int H>
__global__ void k_esum(const void* __restrict__ ei){
    int wide = g_iw;
    int e = blockIdx.x * blockDim.x + threadIdx.x;
    if (e >= E_TOT) return;
    int src, dst; edge_sd(ei, wide, e, src, dst);
    #pragma unroll
    for (int h = 0; h < H; h++){
        float val = lrelu(finz(g_es[src * H + h]) + finz(g_ed[dst * H + h]));
        float w = expc(val - g_m[dst * H + h]);
        g_alpha[(size_t)e * H + h] = w;
        atomicAdd(&g_z[dst * H + h], w);
    }
}

template<int H, int O, int C>
__global__ void k_scatter(const void* __restrict__ ei){
    int wide = g_iw;
    int idx = blockIdx.x * blockDim.x + threadIdx.x;
    if (idx >= E_TOT * C) return;
    int e = idx / C, c = idx - e * C;
    int src, dst; edge_sd(ei, wide, e, src, dst);
    int h = c / O;
    float a = g_alpha[(size_t)e * H + h] / (g_z[dst * H + h] + 1e-16f);
    float v = finz(g_T[(size_t)src * C + c]) * a;
    atomicAdd(&g_O[(size_t)dst * C + c], v);
}

template<int C, bool LEAKY>
__global__ void k_bias(const void* __restrict__ bias, int slot_b){
    int dtb = g_dt[slot_b];
    int idx = blockIdx.x * blockDim.x + threadIdx.x;
    if (idx >= N_NODES * C) return;
    int c = idx % C;
    float o = finz(g_O[idx]) + ldin(bias, dtb, c);
    if (LEAKY) o = lrelu(o);
    g_H[idx] = finz(o);
}

// ---------------- pooling ----------------
__global__ void k_poolA(const void* __restrict__ batch){
    int wide = g_iw;
    int idx = blockIdx.x * blockDim.x + threadIdx.x;
    if (idx >= N_NODES * 128) return;
    int n = idx >> 7, c = idx & 127;
    int b = clampi(ldi(batch, wide, n), 0, N_GRAPHS - 1);
    atomicAdd(&g_gsum[b * 128 + c], finz(g_H[(size_t)n * 128 + c]));
}

__global__ void k_poolB(const void* __restrict__ batch){
    int wide = g_iw;
    int n = blockIdx.x * blockDim.x + threadIdx.x;
    if (n >= N_NODES) return;
    int b = clampi(ldi(batch, wide, n), 0, N_GRAPHS - 1);
    atomicAdd(&g_gcnt[b], 1.f);
}

// output is float32 (established r13/r14)
__global__ void k_fin(float* __restrict__ out){
    int idx = blockIdx.x * blockDim.x + threadIdx.x;
    if (idx >= N_GRAPHS * 128) return;
    int b = idx >> 7, c = idx & 127;
    out[b * 256 + c] = finz(finz(g_gsum[idx]) / fmaxf(g_gcnt[b], 1.f));
}

// ---------------- location-encoder MLP: fast two-stage (LDS) ----------------
// Stage 1: 256 threads each compute hs[j] = sum_l tanh(loc[b,l,:]@Wl1[:,j]+bl1[j])
// Stage 2: 128 threads compute out[b,128+t] = hs@Wl2[:,t]/50 + bl2[t]
// ~50 tanh/thread, then 256-term dot: microseconds for 64 blocks.
__global__ void k_loc(const void* __restrict__ loc, const void* __restrict__ Wl1,
                      const void* __restrict__ bl1, const void* __restrict__ Wl2,
                      const void* __restrict__ bl2, float* __restrict__ out){
    int dtl = g_dt[1], dtw1 = g_dt[16], dtb1 = g_dt[17], dtw2 = g_dt[18], dtb2 = g_dt[19];
    int b = blockIdx.x, t = threadIdx.x;   // 64 blocks x 256 threads
    __shared__ float hs[256];
    float w0 = ldin(Wl1, dtw1, t);             // Wl1[0][t], row-major [2,256]
    float w1 = ldin(Wl1, dtw1, 256 + t);       // Wl1[1][t]
    float bb = ldin(bl1, dtb1, t);
    float s = 0.f;
    #pragma unroll 5
    for (int l = 0; l < N_LOCS; l++){
        float x0 = ldin(loc, dtl, ((size_t)b * N_LOCS + l) * 2);
        float x1 = ldin(loc, dtl, ((size_t)b * N_LOCS + l) * 2 + 1);
        s += tanhf(x0 * w0 + x1 * w1 + bb);
    }
    hs[t] = s;
    __syncthreads();
    if (t < 128){
        float acc = 0.f;
        #pragma unroll 8
        for (int j = 0; j < 256; j++) acc += hs[j] * ldin(Wl2, dtw2, (size_t)j * 128 + t);
        out[(size_t)b * 256 + 128 + t] = finz(acc * (1.f / (float)N_LOCS) + ldin(bl2, dtb2, t));
    }
}

// ---------------- per-layer driver ----------------
template<int H, int O, int C, bool LEAKY>
static void gat_layer(const void* ei, const void* as, const void* ad, const void* bias,
                      int s_as, int s_ad, int s_b, hipStream_t stream){
    const int EB  = (E_TOT + 255) / 256;
    const int NC  = (N_NODES * C + 255) / 256;
    const int NH  = (N_NODES * H + 255) / 256;
    const int EC  = (int)(((long long)E_TOT * C + 255) / 256);
    k_esed<H, O, C><<<NH, 256, 0, stream>>>(as, ad, s_as, s_ad);
    k_zero_layer<H, C><<<NC, 256, 0, stream>>>();
    k_emax<H><<<EB, 256, 0, stream>>>(ei);
    k_mfin<H><<<NH, 256, 0, stream>>>();
    k_esum<H><<<EB, 256, 0, stream>>>(ei);
    k_scatter<H, O, C><<<EC, 256, 0, stream>>>(ei);
    k_bias<C, LEAKY><<<NC, 256, 0, stream>>>(bias, s_b);
}

// ---------------- launch ----------------
extern "C" void kernel_launch(void* const* d_in, const int* in_sizes, int n_in,
                              void* d_out, int out_size, void* d_ws, size_t ws_size,
                              hipStream_t stream){
    static const int want[20] = {300000, 6400, 1600000, 50000,
                                 774, 129, 129, 129,
                                 16641, 129, 129, 129,
                                 16512, 128, 128, 128,
                                 512, 256, 32768, 128};
    const void* P[20];
    bool assigned[20];
    for (int s = 0; s < 20; s++){ P[s] = nullptr; assigned[s] = false; }
    bool ok = (n_in == 20);
    if (ok){
        for (int i = 0; i < 20; i++){
            int sz = in_sizes[i], hit = -1;
            for (int s = 0; s < 20; s++)
                if (!assigned[s] && want[s] == sz){ hit = s; break; }
            if (hit < 0){ ok = false; break; }
            P[hit] = d_in[i]; assigned[hit] = true;
        }
        for (int s = 0; s < 20 && ok; s++) if (!assigned[s]) ok = false;
    }
    if (!ok) for (int s = 0; s < 20 && s < n_in; s++) P[s] = d_in[s];

    const void* x    = P[0];
    const void* loc  = P[1];
    const void* ei   = P[2];
    const void* batch= P[3];
    const void* W0   = P[4];
    const void* as0  = P[5];
    const void* ad0  = P[6];
    const void* b0   = P[7];
    const void* W1   = P[8];
    const void* as1  = P[9];
    const void* ad1  = P[10];
    const void* b1   = P[11];
    const void* W2   = P[12];
    const void* as2  = P[13];
    const void* ad2  = P[14];
    const void* b2   = P[15];
    const void* Wl1  = P[16];
    const void* bl1  = P[17];
    const void* Wl2  = P[18];
    const void* bl2  = P[19];
    float* out = (float*)d_out;
    (void)d_ws; (void)ws_size; (void)out_size;

    k_detect<<<1, 64, 0, stream>>>(x, loc, W0, as0, ad0, W1, as1, ad1, W2, as2, ad2, Wl1, Wl2, ei);
    k_zero_global<<<(N_GRAPHS * 128 + 255) / 256, 256, 0, stream>>>();

    // layer 0
    k_gemm0<<<(N_NODES * 129 + 255) / 256, 256, 0, stream>>>(x, W0);
    gat_layer<3, 43, 129, true>(ei, as0, ad0, b0, 5, 6, 7, stream);

    // layer 1
    k_gemm<129, 129><<<(N_NODES * 129 + 255) / 256, 256, 0, stream>>>(W1, 8);
    gat_layer<3, 43, 129, true>(ei, as1, ad1, b1, 9, 10, 11, stream);

    // layer 2
    k_gemm<129, 128><<<(N_NODES * 128 + 255) / 256, 256, 0, stream>>>(W2, 12);
    gat_layer<1, 128, 128, false>(ei, as2, ad2, b2, 13, 14, 15, stream);

    // pooling + output (f32 stores)
    k_poolA<<<(N_NODES * 128 + 255) / 256, 256, 0, stream>>>(batch);
    k_poolB<<<(N_NODES + 255) / 256, 256, 0, stream>>>(batch);
    k_fin  <<<(N_GRAPHS * 128 + 255) / 256, 256, 0, stream>>>(out);
    k_loc  <<<N_GRAPHS, 256, 0, stream>>>(loc, Wl1, bl1, Wl2, bl2, out);
}

// Round 16
// 2631.752 us; speedup vs baseline: 2.3675x; 1.2208x over previous
//
#include <hip/hip_runtime.h>
#include <hip/hip_bf16.h>
#include <math.h>

#define N_NODES  50000
#define N_EDGES  800000
#define E_TOT    850000   /* edges + self loops */
#define N_GRAPHS 64
#define N_LOCS   50

typedef __hip_bfloat16 bf16;

// ---------------- static scratch ----------------
__device__ int      g_dt[20];                    // float inputs: 0=bf16, 1=f32, 2=f64
__device__ int      g_iw;                        // int inputs: 1 = int64, 0 = int32
__device__ int      g_deg[N_NODES];
__device__ int      g_cursor[N_NODES];
__device__ int      g_rowptr[N_NODES + 1];
__device__ int      g_csrc[E_TOT];               // CSR: src node per slot
__device__ int      g_cedge[E_TOT];              // CSR: edge id per slot (alpha index)
__device__ float    g_T[(size_t)N_NODES * 129];  // transformed features (this layer)
__device__ float    g_H[(size_t)N_NODES * 129];  // layer output (next layer input)
__device__ float    g_es[N_NODES * 3];
__device__ float    g_ed[N_NODES * 3];
__device__ unsigned g_mkey[N_NODES * 3];         // segment-max keys
__device__ float    g_m[N_NODES * 3];            // segment max (finite, 0 if empty)
__device__ float    g_z[N_NODES * 3];            // exp-sum
__device__ float    g_alpha[(size_t)E_TOT * 3];  // unnormalized exp weights per edge/head
__device__ float    g_gsum[N_GRAPHS * 128];
__device__ float    g_gcnt[N_GRAPHS];

// ---------------- helpers ----------------
__device__ __forceinline__ float b2f(bf16 x){ return __bfloat162float(x); }
__device__ __forceinline__ float lrelu(float x){ return x > 0.f ? x : 0.2f * x; }
__device__ __forceinline__ int   clampi(int v, int lo, int hi){ return v < lo ? lo : (v > hi ? hi : v); }
__device__ __forceinline__ float finz(float v){
    unsigned u = __float_as_uint(v);
    return ((u & 0x7F800000u) == 0x7F800000u) ? 0.f : v;   // NaN/inf -> 0
}
// dtype-dispatching sanitized float input load: 0=bf16, 1=f32, 2=f64
__device__ __forceinline__ float ldin(const void* p, int m, size_t i){
    float v = (m == 2) ? (float)((const double*)p)[i]
            : (m == 1) ? ((const float*)p)[i]
            :            b2f(((const bf16*)p)[i]);
    return finz(v);
}
__device__ __forceinline__ int ldi(const void* p, int wide, size_t i){
    return wide ? (int)((const long long*)p)[i] : ((const int*)p)[i];
}
__device__ __forceinline__ float expc(float a){ return __expf(fminf(fmaxf(a, -80.f), 0.f)); }
// order-preserving float<->unsigned key (0 reserved as "empty" sentinel)
__device__ __forceinline__ unsigned fkey(float f){
    unsigned u = __float_as_uint(f);
    return (u & 0x80000000u) ? ~u : (u | 0x80000000u);
}
__device__ __forceinline__ float kinv(unsigned k){
    return __uint_as_float((k & 0x80000000u) ? (k ^ 0x80000000u) : ~k);
}
// edge -> (src,dst) including self-loops
__device__ __forceinline__ void edge_sd(const void* ei, int wide, int e, int& src, int& dst){
    if (e < N_EDGES){
        src = clampi(ldi(ei, wide, e), 0, N_NODES - 1);
        dst = clampi(ldi(ei, wide, (size_t)N_EDGES + e), 0, N_NODES - 1);
    } else {
        src = dst = e - N_EDGES;
    }
}

// ---------------- dtype detection (1 wave) ----------------
__global__ void k_detect(const void* x, const void* loc, const void* W0,
                         const void* as0, const void* ad0, const void* W1,
                         const void* as1, const void* ad1, const void* W2,
                         const void* as2, const void* ad2, const void* Wl1,
                         const void* Wl2, const void* ei){
    const void* ps[13] = {x, loc, W0, as0, ad0, W1, as1, ad1, W2, as2, ad2, Wl1, Wl2};
    const int  sl[13]  = {0,  1,   4,  5,   6,   8,  9,   10,  12, 13,  14,  16,  18};
    int lane = threadIdx.x;   // 64 lanes
    for (int t = 0; t < 13; t++){
        float vf = ((const float*)ps[t])[lane];
        unsigned uf = __float_as_uint(vf);
        bool hit64 = ((uf & 0x7F800000u) == 0x7F800000u) || fabsf(vf) > 1e4f;
        int n64 = __popcll(__ballot(hit64));

        float vb = b2f(((const bf16*)ps[t])[lane]);
        unsigned ub = __float_as_uint(vb);
        bool hit32 = ((ub & 0x7F800000u) == 0x7F800000u) || fabsf(vb) > 1e4f;
        int n32 = __popcll(__ballot(hit32));

        if (lane == 0) g_dt[sl[t]] = (n64 >= 2) ? 2 : ((n32 >= 2) ? 1 : 0);
    }
    int w0 = ((const int*)ei)[lane];
    unsigned long long zm = __ballot((lane & 1) && (w0 == 0));
    if (lane == 0){
        g_iw = (__popcll(zm) >= 16) ? 1 : 0;
        g_dt[2] = g_dt[3] = 0;
        g_dt[7] = g_dt[11] = g_dt[15] = 0;
        g_dt[17] = g_dt[19] = 0;
    }
}

// ---------------- zero init ----------------
__global__ void k_zero_global(){
    int i = blockIdx.x * blockDim.x + threadIdx.x;
    if (i < N_NODES) g_deg[i] = 0;
    if (i < N_GRAPHS * 128) g_gsum[i] = 0.f;
    if (i < N_GRAPHS) g_gcnt[i] = 0.f;
}
template<int H>
__global__ void k_zero_layer(){
    int i = blockIdx.x * blockDim.x + threadIdx.x;
    if (i < N_NODES * H){ g_mkey[i] = 0u; g_z[i] = 0.f; }
}

// ---------------- CSR build (once per call) ----------------
__global__ void k_deg(const void* __restrict__ ei){
    int wide = g_iw;
    int e = blockIdx.x * blockDim.x + threadIdx.x;
    if (e >= E_TOT) return;
    int src, dst; edge_sd(ei, wide, e, src, dst);
    atomicAdd(&g_deg[dst], 1);
}

__global__ void k_scan(){
    int lane = threadIdx.x;           // 64 lanes, 1 block
    int carry = 0;
    for (int base = 0; base < N_NODES; base += 64){
        int i = base + lane;
        int v = (i < N_NODES) ? g_deg[i] : 0;
        int s = v;
        #pragma unroll
        for (int off = 1; off < 64; off <<= 1){
            int t = __shfl_up(s, off);
            if (lane >= off) s += t;
        }
        int excl = carry + s - v;
        if (i < N_NODES){ g_rowptr[i] = excl; g_cursor[i] = excl; }
        carry += __shfl(s, 63);
    }
    if (lane == 0) g_rowptr[N_NODES] = carry;   // == E_TOT
}

__global__ void k_fillcsr(const void* __restrict__ ei){
    int wide = g_iw;
    int e = blockIdx.x * blockDim.x + threadIdx.x;
    if (e >= E_TOT) return;
    int src, dst; edge_sd(ei, wide, e, src, dst);
    int pos = atomicAdd(&g_cursor[dst], 1);
    if (pos >= 0 && pos < E_TOT){ g_csrc[pos] = src; g_cedge[pos] = e; }
}

// ---------------- GEMMs ----------------
__global__ void k_gemm0(const void* __restrict__ x, const void* __restrict__ W){
    int dtx = g_dt[0], dtw = g_dt[4];
    int idx = blockIdx.x * blockDim.x + threadIdx.x;
    if (idx >= N_NODES * 129) return;
    int n = idx / 129, c = idx - n * 129;
    float acc = 0.f;
    #pragma unroll
    for (int k = 0; k < 6; k++)
        acc += ldin(x, dtx, (size_t)n * 6 + k) * ldin(W, dtw, k * 129 + c);
    g_T[idx] = finz(acc);
}

template<int K, int CO>
__global__ void k_gemm(const void* __restrict__ W, int slot){
    int dtw = g_dt[slot];
    int idx = blockIdx.x * blockDim.x + threadIdx.x;
    if (idx >= N_NODES * CO) return;
    int n = idx / CO, c = idx - n * CO;
    const float* ar = g_H + (size_t)n * K;
    float acc = 0.f;
    #pragma unroll 4
    for (int k = 0; k < K; k++) acc += finz(ar[k]) * ldin(W, dtw, k * CO + c);
    g_T[(size_t)n * CO + c] = finz(acc);
}

// ---------------- per-node attention coefficients ----------------
template<int H, int O, int C>
__global__ void k_esed(const void* __restrict__ as, const void* __restrict__ ad,
                       int slot_as, int slot_ad){
    int dta = g_dt[slot_as], dtd = g_dt[slot_ad];
    int idx = blockIdx.x * blockDim.x + threadIdx.x;
    if (idx >= N_NODES * H) return;
    int n = idx / H, h = idx - n * H;
    const float* tr = g_T + (size_t)n * C + h * O;
    float a = 0.f, b = 0.f;
    #pragma unroll 4
    for (int o = 0; o < O; o++){
        float v = finz(tr[o]);
        a += v * ldin(as, dta, h * O + o);
        b += v * ldin(ad, dtd, h * O + o);
    }
    g_es[idx] = finz(a); g_ed[idx] = finz(b);
}

// ---------------- edge-parallel softmax stats (atomic, validated) ----------
template<int H>
__global__ void k_emax(const void* __restrict__ ei){
    int wide = g_iw;
    int e = blockIdx.x * blockDim.x + threadIdx.x;
    if (e >= E_TOT) return;
    int src, dst; edge_sd(ei, wide, e, src, dst);
    #pragma unroll
    for (int h = 0; h < H; h++){
        float val = lrelu(finz(g_es[src * H + h]) + finz(g_ed[dst * H + h]));
        atomicMax(&g_mkey[dst * H + h], fkey(val));
    }
}

template<int H>
__global__ void k_mfin(){
    int idx = blockIdx.x * blockDim.x + threadIdx.x;
    if (idx >= N_NODES * H) return;
    unsigned k = g_mkey[idx];
    g_m[idx] = (k == 0u) ? 0.f : finz(kinv(k));
}

template<int H>
__global__ void k_esum(const void* __restrict__ ei){
    int wide = g_iw;
    int e = blockIdx.x * blockDim.x + threadIdx.x;
    if (e >= E_TOT) return;
    int src, dst; edge_sd(ei, wide, e, src, dst);
    #pragma unroll
    for (int h = 0; h < H; h++){
        float val = lrelu(finz(g_es[src * H + h]) + finz(g_ed[dst * H + h]));
        float w = expc(val - g_m[dst * H + h]);
        g_alpha[(size_t)e * H + h] = w;
        atomicAdd(&g_z[dst * H + h], w);
    }
}

// ---------------- CSR gather: one wave per dst node, no atomics -------------
// Replaces k_scatter + k_bias + g_O zeroing. Lanes cover channels
// {lane, lane+64, (128 on lane0 if C>128)}; serial over in-edges.
template<int H, int O, int C, bool LEAKY>
__global__ __launch_bounds__(256)
void k_gather(const void* __restrict__ bias, int slot_b){
    int dtb = g_dt[slot_b];
    int wv = threadIdx.x >> 6, lane = threadIdx.x & 63;
    int n = blockIdx.x * 4 + wv;
    if (n >= N_NODES) return;
    int r0 = clampi(g_rowptr[n], 0, E_TOT);
    int r1 = clampi(g_rowptr[n + 1], r0, E_TOT);

    float inv[H];
    #pragma unroll
    for (int h = 0; h < H; h++) inv[h] = 1.f / (finz(g_z[n * H + h]) + 1e-16f);

    const int h0 = lane / O;
    const int h1 = (lane + 64) / O;
    float iv0 = inv[h0], iv1 = inv[h1], ivL = inv[H - 1];
    float a0 = 0.f, a1 = 0.f, a2 = 0.f;
    for (int i = r0; i < r1; i++){
        int src = clampi(g_csrc[i], 0, N_NODES - 1);
        int e   = clampi(g_cedge[i], 0, E_TOT - 1);
        const float* tr = g_T + (size_t)src * C;
        float w0 = g_alpha[(size_t)e * H + h0] * iv0;
        float w1 = g_alpha[(size_t)e * H + h1] * iv1;
        a0 += finz(tr[lane]) * w0;
        a1 += finz(tr[lane + 64]) * w1;
        if (C > 128 && lane == 0)
            a2 += finz(tr[128]) * g_alpha[(size_t)e * H + H - 1] * ivL;
    }
    float o0 = finz(a0) + ldin(bias, dtb, lane);
    float o1 = finz(a1) + ldin(bias, dtb, lane + 64);
    if (LEAKY){ o0 = lrelu(o0); o1 = lrelu(o1); }
    g_H[(size_t)n * C + lane] = finz(o0);
    g_H[(size_t)n * C + lane + 64] = finz(o1);
    if (C > 128 && lane == 0){
        float o2 = finz(a2) + ldin(bias, dtb, 128);
        if (LEAKY) o2 = lrelu(o2);
        g_H[(size_t)n * C + 128] = finz(o2);
    }
}

// ---------------- pooling ----------------
__global__ void k_poolA(const void* __restrict__ batch){
    int wide = g_iw;
    int idx = blockIdx.x * blockDim.x + threadIdx.x;
    if (idx >= N_NODES * 128) return;
    int n = idx >> 7, c = idx & 127;
    int b = clampi(ldi(batch, wide, n), 0, N_GRAPHS - 1);
    atomicAdd(&g_gsum[b * 128 + c], finz(g_H[(size_t)n * 128 + c]));
}

__global__ void k_poolB(const void* __restrict__ batch){
    int wide = g_iw;
    int n = blockIdx.x * blockDim.x + threadIdx.x;
    if (n >= N_NODES) return;
    int b = clampi(ldi(batch, wide, n), 0, N_GRAPHS - 1);
    atomicAdd(&g_gcnt[b], 1.f);
}

// output is float32 (established r13/r14)
__global__ void k_fin(float* __restrict__ out){
    int idx = blockIdx.x * blockDim.x + threadIdx.x;
    if (idx >= N_GRAPHS * 128) return;
    int b = idx >> 7, c = idx & 127;
    out[b * 256 + c] = finz(finz(g_gsum[idx]) / fmaxf(g_gcnt[b], 1.f));
}

// ---------------- location-encoder MLP: fast two-stage (LDS) ----------------
__global__ void k_loc(const void* __restrict__ loc, const void* __restrict__ Wl1,
                      const void* __restrict__ bl1, const void* __restrict__ Wl2,
                      const void* __restrict__ bl2, float* __restrict__ out){
    int dtl = g_dt[1], dtw1 = g_dt[16], dtb1 = g_dt[17], dtw2 = g_dt[18], dtb2 = g_dt[19];
    int b = blockIdx.x, t = threadIdx.x;   // 64 blocks x 256 threads
    __shared__ float hs[256];
    float w0 = ldin(Wl1, dtw1, t);
    float w1 = ldin(Wl1, dtw1, 256 + t);
    float bb = ldin(bl1, dtb1, t);
    float s = 0.f;
    #pragma unroll 5
    for (int l = 0; l < N_LOCS; l++){
        float x0 = ldin(loc, dtl, ((size_t)b * N_LOCS + l) * 2);
        float x1 = ldin(loc, dtl, ((size_t)b * N_LOCS + l) * 2 + 1);
        s += tanhf(x0 * w0 + x1 * w1 + bb);
    }
    hs[t] = s;
    __syncthreads();
    if (t < 128){
        float acc = 0.f;
        #pragma unroll 8
        for (int j = 0; j < 256; j++) acc += hs[j] * ldin(Wl2, dtw2, (size_t)j * 128 + t);
        out[(size_t)b * 256 + 128 + t] = finz(acc * (1.f / (float)N_LOCS) + ldin(bl2, dtb2, t));
    }
}

// ---------------- per-layer driver ----------------
template<int H, int O, int C, bool LEAKY>
static void gat_layer(const void* ei, const void* as, const void* ad, const void* bias,
                      int s_as, int s_ad, int s_b, hipStream_t stream){
    const int EB  = (E_TOT + 255) / 256;
    const int NH  = (N_NODES * H + 255) / 256;
    const int GB  = (N_NODES + 3) / 4;          // one wave per node
    k_esed<H, O, C><<<NH, 256, 0, stream>>>(as, ad, s_as, s_ad);
    k_zero_layer<H><<<NH, 256, 0, stream>>>();
    k_emax<H><<<EB, 256, 0, stream>>>(ei);
    k_mfin<H><<<NH, 256, 0, stream>>>();
    k_esum<H><<<EB, 256, 0, stream>>>(ei);
    k_gather<H, O, C, LEAKY><<<GB, 256, 0, stream>>>(bias, s_b);
}

// ---------------- launch ----------------
extern "C" void kernel_launch(void* const* d_in, const int* in_sizes, int n_in,
                              void* d_out, int out_size, void* d_ws, size_t ws_size,
                              hipStream_t stream){
    static const int want[20] = {300000, 6400, 1600000, 50000,
                                 774, 129, 129, 129,
                                 16641, 129, 129, 129,
                                 16512, 128, 128, 128,
                                 512, 256, 32768, 128};
    const void* P[20];
    bool assigned[20];
    for (int s = 0; s < 20; s++){ P[s] = nullptr; assigned[s] = false; }
    bool ok = (n_in == 20);
    if (ok){
        for (int i = 0; i < 20; i++){
            int sz = in_sizes[i], hit = -1;
            for (int s = 0; s < 20; s++)
                if (!assigned[s] && want[s] == sz){ hit = s; break; }
            if (hit < 0){ ok = false; break; }
            P[hit] = d_in[i]; assigned[hit] = true;
        }
        for (int s = 0; s < 20 && ok; s++) if (!assigned[s]) ok = false;
    }
    if (!ok) for (int s = 0; s < 20 && s < n_in; s++) P[s] = d_in[s];

    const void* x    = P[0];
    const void* loc  = P[1];
    const void* ei   = P[2];
    const void* batch= P[3];
    const void* W0   = P[4];
    const void* as0  = P[5];
    const void* ad0  = P[6];
    const void* b0   = P[7];
    const void* W1   = P[8];
    const void* as1  = P[9];
    const void* ad1  = P[10];
    const void* b1   = P[11];
    const void* W2   = P[12];
    const void* as2  = P[13];
    const void* ad2  = P[14];
    const void* b2   = P[15];
    const void* Wl1  = P[16];
    const void* bl1  = P[17];
    const void* Wl2  = P[18];
    const void* bl2  = P[19];
    float* out = (float*)d_out;
    (void)d_ws; (void)ws_size; (void)out_size;

    const int EB = (E_TOT + 255) / 256;
    k_detect<<<1, 64, 0, stream>>>(x, loc, W0, as0, ad0, W1, as1, ad1, W2, as2, ad2, Wl1, Wl2, ei);
    k_zero_global<<<(N_NODES + 255) / 256, 256, 0, stream>>>();

    // CSR build (graph shared by all 3 layers)
    k_deg    <<<EB, 256, 0, stream>>>(ei);
    k_scan   <<<1, 64, 0, stream>>>();
    k_fillcsr<<<EB, 256, 0, stream>>>(ei);

    // layer 0
    k_gemm0<<<(N_NODES * 129 + 255) / 256, 256, 0, stream>>>(x, W0);
    gat_layer<3, 43, 129, true>(ei, as0, ad0, b0, 5, 6, 7, stream);

    // layer 1
    k_gemm<129, 129><<<(N_NODES * 129 + 255) / 256, 256, 0, stream>>>(W1, 8);
    gat_layer<3, 43, 129, true>(ei, as1, ad1, b1, 9, 10, 11, stream);

    // layer 2
    k_gemm<129, 128><<<(N_NODES * 128 + 255) / 256, 256, 0, stream>>>(W2, 12);
    gat_layer<1, 128, 128, false>(ei, as2, ad2, b2, 13, 14, 15, stream);

    // pooling + output (f32 stores)
    k_poolA<<<(N_NODES * 128 + 255) / 256, 256, 0, stream>>>(batch);
    k_poolB<<<(N_NODES + 255) / 256, 256, 0, stream>>>(batch);
    k_fin  <<<(N_GRAPHS * 128 + 255) / 256, 256, 0, stream>>>(out);
    k_loc  <<<N_GRAPHS, 256, 0, stream>>>(loc, Wl1, bl1, Wl2, bl2, out);
}

// Round 17
// 2278.791 us; speedup vs baseline: 2.7342x; 1.1549x over previous
//
#include <hip/hip_runtime.h>
#include <hip/hip_bf16.h>
#include <math.h>

#define N_NODES  50000
#define N_EDGES  800000
#define E_TOT    850000   /* edges + self loops */
#define N_GRAPHS 64
#define N_LOCS   50
#define SCAN_B   ((N_NODES + 255) / 256)   /* 196 scan blocks */

typedef __hip_bfloat16 bf16;

// ---------------- static scratch ----------------
__device__ int      g_dt[20];                    // float inputs: 0=bf16, 1=f32, 2=f64
__device__ int      g_iw;                        // int inputs: 1 = int64, 0 = int32
__device__ int      g_deg[N_NODES];
__device__ int      g_cursor[N_NODES];
__device__ int      g_rowptr[N_NODES + 1];
__device__ int      g_bsum[SCAN_B];
__device__ int      g_csrc[E_TOT];               // CSR: src node per slot
__device__ int      g_cedge[E_TOT];              // CSR: edge id per slot (alpha index)
__device__ float    g_T[(size_t)N_NODES * 129];  // transformed features (this layer)
__device__ float    g_H[(size_t)N_NODES * 129];  // layer output (next layer input)
__device__ float    g_es[N_NODES * 3];
__device__ float    g_ed[N_NODES * 3];
__device__ unsigned g_mkey[N_NODES * 3];         // segment-max keys
__device__ float    g_m[N_NODES * 3];            // segment max (finite, 0 if empty)
__device__ float    g_z[N_NODES * 3];            // exp-sum
__device__ float    g_alpha[(size_t)E_TOT * 3];  // unnormalized exp weights per edge/head
__device__ float    g_gsum[N_GRAPHS * 128];
__device__ float    g_gcnt[N_GRAPHS];

// ---------------- helpers ----------------
__device__ __forceinline__ float b2f(bf16 x){ return __bfloat162float(x); }
__device__ __forceinline__ float lrelu(float x){ return x > 0.f ? x : 0.2f * x; }
__device__ __forceinline__ int   clampi(int v, int lo, int hi){ return v < lo ? lo : (v > hi ? hi : v); }
__device__ __forceinline__ float finz(float v){
    unsigned u = __float_as_uint(v);
    return ((u & 0x7F800000u) == 0x7F800000u) ? 0.f : v;   // NaN/inf -> 0
}
// dtype-dispatching sanitized float input load: 0=bf16, 1=f32, 2=f64
__device__ __forceinline__ float ldin(const void* p, int m, size_t i){
    float v = (m == 2) ? (float)((const double*)p)[i]
            : (m == 1) ? ((const float*)p)[i]
            :            b2f(((const bf16*)p)[i]);
    return finz(v);
}
__device__ __forceinline__ int ldi(const void* p, int wide, size_t i){
    return wide ? (int)((const long long*)p)[i] : ((const int*)p)[i];
}
__device__ __forceinline__ float expc(float a){ return __expf(fminf(fmaxf(a, -80.f), 0.f)); }
// order-preserving float<->unsigned key (0 reserved as "empty" sentinel)
__device__ __forceinline__ unsigned fkey(float f){
    unsigned u = __float_as_uint(f);
    return (u & 0x80000000u) ? ~u : (u | 0x80000000u);
}
__device__ __forceinline__ float kinv(unsigned k){
    return __uint_as_float((k & 0x80000000u) ? (k ^ 0x80000000u) : ~k);
}
// edge -> (src,dst) including self-loops
__device__ __forceinline__ void edge_sd(const void* ei, int wide, int e, int& src, int& dst){
    if (e < N_EDGES){
        src = clampi(ldi(ei, wide, e), 0, N_NODES - 1);
        dst = clampi(ldi(ei, wide, (size_t)N_EDGES + e), 0, N_NODES - 1);
    } else {
        src = dst = e - N_EDGES;
    }
}

// ---------------- dtype detection (1 wave) ----------------
__global__ void k_detect(const void* x, const void* loc, const void* W0,
                         const void* as0, const void* ad0, const void* W1,
                         const void* as1, const void* ad1, const void* W2,
                         const void* as2, const void* ad2, const void* Wl1,
                         const void* Wl2, const void* ei){
    const void* ps[13] = {x, loc, W0, as0, ad0, W1, as1, ad1, W2, as2, ad2, Wl1, Wl2};
    const int  sl[13]  = {0,  1,   4,  5,   6,   8,  9,   10,  12, 13,  14,  16,  18};
    int lane = threadIdx.x;   // 64 lanes
    for (int t = 0; t < 13; t++){
        float vf = ((const float*)ps[t])[lane];
        unsigned uf = __float_as_uint(vf);
        bool hit64 = ((uf & 0x7F800000u) == 0x7F800000u) || fabsf(vf) > 1e4f;
        int n64 = __popcll(__ballot(hit64));

        float vb = b2f(((const bf16*)ps[t])[lane]);
        unsigned ub = __float_as_uint(vb);
        bool hit32 = ((ub & 0x7F800000u) == 0x7F800000u) || fabsf(vb) > 1e4f;
        int n32 = __popcll(__ballot(hit32));

        if (lane == 0) g_dt[sl[t]] = (n64 >= 2) ? 2 : ((n32 >= 2) ? 1 : 0);
    }
    int w0 = ((const int*)ei)[lane];
    unsigned long long zm = __ballot((lane & 1) && (w0 == 0));
    if (lane == 0){
        g_iw = (__popcll(zm) >= 16) ? 1 : 0;
        g_dt[2] = g_dt[3] = 0;
        g_dt[7] = g_dt[11] = g_dt[15] = 0;
        g_dt[17] = g_dt[19] = 0;
    }
}

// ---------------- zero init ----------------
__global__ void k_zero_global(){
    int i = blockIdx.x * blockDim.x + threadIdx.x;
    if (i < N_NODES) g_deg[i] = 0;
    if (i < N_GRAPHS * 128) g_gsum[i] = 0.f;
    if (i < N_GRAPHS) g_gcnt[i] = 0.f;
}
template<int H>
__global__ void k_zero_layer(){
    int i = blockIdx.x * blockDim.x + threadIdx.x;
    if (i < N_NODES * H){ g_mkey[i] = 0u; g_z[i] = 0.f; }
}

// ---------------- CSR build (once per call) ----------------
__global__ void k_deg(const void* __restrict__ ei){
    int wide = g_iw;
    int e = blockIdx.x * blockDim.x + threadIdx.x;
    if (e >= E_TOT) return;
    int src, dst; edge_sd(ei, wide, e, src, dst);
    atomicAdd(&g_deg[dst], 1);
}

// 3-stage parallel exclusive scan of g_deg -> g_rowptr/g_cursor
__global__ void k_scan1(){   // per-block inclusive scan (LDS), emit block sum
    __shared__ int s[256];
    int i = blockIdx.x * 256 + threadIdx.x;
    int v = (i < N_NODES) ? g_deg[i] : 0;
    s[threadIdx.x] = v;
    __syncthreads();
    for (int off = 1; off < 256; off <<= 1){
        int add = (threadIdx.x >= off) ? s[threadIdx.x - off] : 0;
        __syncthreads();
        s[threadIdx.x] += add;
        __syncthreads();
    }
    if (threadIdx.x == 255) g_bsum[blockIdx.x] = s[255];
    if (i < N_NODES) g_rowptr[i] = s[threadIdx.x] - v;   // intra-block exclusive
}

__global__ void k_scan2(){   // 1 wave scans the 196 block sums (exclusive)
    int lane = threadIdx.x;
    int carry = 0;
    for (int base = 0; base < SCAN_B; base += 64){
        int i = base + lane;
        int v = (i < SCAN_B) ? g_bsum[i] : 0;
        int s = v;
        #pragma unroll
        for (int off = 1; off < 64; off <<= 1){
            int t = __shfl_up(s, off);
            if (lane >= off) s += t;
        }
        if (i < SCAN_B) g_bsum[i] = carry + s - v;
        carry += __shfl(s, 63);
    }
    if (lane == 0) g_rowptr[N_NODES] = carry;   // == E_TOT
}

__global__ void k_scan3(){   // add block offsets
    int i = blockIdx.x * 256 + threadIdx.x;
    if (i < N_NODES){
        int r = g_rowptr[i] + g_bsum[blockIdx.x];
        g_rowptr[i] = r;
        g_cursor[i] = r;
    }
}

__global__ void k_fillcsr(const void* __restrict__ ei){
    int wide = g_iw;
    int e = blockIdx.x * blockDim.x + threadIdx.x;
    if (e >= E_TOT) return;
    int src, dst; edge_sd(ei, wide, e, src, dst);
    int pos = atomicAdd(&g_cursor[dst], 1);
    if (pos >= 0 && pos < E_TOT){ g_csrc[pos] = src; g_cedge[pos] = e; }
}

// ---------------- GEMMs ----------------
__global__ void k_gemm0(const void* __restrict__ x, const void* __restrict__ W){
    int dtx = g_dt[0], dtw = g_dt[4];
    int idx = blockIdx.x * blockDim.x + threadIdx.x;
    if (idx >= N_NODES * 129) return;
    int n = idx / 129, c = idx - n * 129;
    float acc = 0.f;
    #pragma unroll
    for (int k = 0; k < 6; k++)
        acc += ldin(x, dtx, (size_t)n * 6 + k) * ldin(W, dtw, k * 129 + c);
    g_T[idx] = finz(acc);
}

template<int K, int CO>
__global__ void k_gemm(const void* __restrict__ W, int slot){
    int dtw = g_dt[slot];
    int idx = blockIdx.x * blockDim.x + threadIdx.x;
    if (idx >= N_NODES * CO) return;
    int n = idx / CO, c = idx - n * CO;
    const float* ar = g_H + (size_t)n * K;
    float acc = 0.f;
    #pragma unroll 4
    for (int k = 0; k < K; k++) acc += finz(ar[k]) * ldin(W, dtw, k * CO + c);
    g_T[(size_t)n * CO + c] = finz(acc);
}

// ---------------- per-node attention coefficients ----------------
template<int H, int O, int C>
__global__ void k_esed(const void* __restrict__ as, const void* __restrict__ ad,
                       int slot_as, int slot_ad){
    int dta = g_dt[slot_as], dtd = g_dt[slot_ad];
    int idx = blockIdx.x * blockDim.x + threadIdx.x;
    if (idx >= N_NODES * H) return;
    int n = idx / H, h = idx - n * H;
    const float* tr = g_T + (size_t)n * C + h * O;
    float a = 0.f, b = 0.f;
    #pragma unroll 4
    for (int o = 0; o < O; o++){
        float v = finz(tr[o]);
        a += v * ldin(as, dta, h * O + o);
        b += v * ldin(ad, dtd, h * O + o);
    }
    g_es[idx] = finz(a); g_ed[idx] = finz(b);
}

// ---------------- edge-parallel softmax stats (atomic, validated) ----------
template<int H>
__global__ void k_emax(const void* __restrict__ ei){
    int wide = g_iw;
    int e = blockIdx.x * blockDim.x + threadIdx.x;
    if (e >= E_TOT) return;
    int src, dst; edge_sd(ei, wide, e, src, dst);
    #pragma unroll
    for (int h = 0; h < H; h++){
        float val = lrelu(finz(g_es[src * H + h]) + finz(g_ed[dst * H + h]));
        atomicMax(&g_mkey[dst * H + h], fkey(val));
    }
}

template<int H>
__global__ void k_mfin(){
    int idx = blockIdx.x * blockDim.x + threadIdx.x;
    if (idx >= N_NODES * H) return;
    unsigned k = g_mkey[idx];
    g_m[idx] = (k == 0u) ? 0.f : finz(kinv(k));
}

template<int H>
__global__ void k_esum(const void* __restrict__ ei){
    int wide = g_iw;
    int e = blockIdx.x * blockDim.x + threadIdx.x;
    if (e >= E_TOT) return;
    int src, dst; edge_sd(ei, wide, e, src, dst);
    #pragma unroll
    for (int h = 0; h < H; h++){
        float val = lrelu(finz(g_es[src * H + h]) + finz(g_ed[dst * H + h]));
        float w = expc(val - g_m[dst * H + h]);
        g_alpha[(size_t)e * H + h] = w;
        atomicAdd(&g_z[dst * H + h], w);
    }
}

// ---------------- CSR gather: one wave per dst node, no atomics -------------
template<int H, int O, int C, bool LEAKY>
__global__ __launch_bounds__(256)
void k_gather(const void* __restrict__ bias, int slot_b){
    int dtb = g_dt[slot_b];
    int wv = threadIdx.x >> 6, lane = threadIdx.x & 63;
    int n = blockIdx.x * 4 + wv;
    if (n >= N_NODES) return;
    int r0 = clampi(g_rowptr[n], 0, E_TOT);
    int r1 = clampi(g_rowptr[n + 1], r0, E_TOT);

    float inv[H];
    #pragma unroll
    for (int h = 0; h < H; h++) inv[h] = 1.f / (finz(g_z[n * H + h]) + 1e-16f);

    const int h0 = lane / O;
    const int h1 = (lane + 64) / O;
    float iv0 = inv[h0], iv1 = inv[h1], ivL = inv[H - 1];
    float a0 = 0.f, a1 = 0.f, a2 = 0.f;
    for (int i = r0; i < r1; i++){
        int src = clampi(g_csrc[i], 0, N_NODES - 1);
        int e   = clampi(g_cedge[i], 0, E_TOT - 1);
        const float* tr = g_T + (size_t)src * C;
        float w0 = g_alpha[(size_t)e * H + h0] * iv0;
        float w1 = g_alpha[(size_t)e * H + h1] * iv1;
        a0 += finz(tr[lane]) * w0;
        a1 += finz(tr[lane + 64]) * w1;
        if (C > 128 && lane == 0)
            a2 += finz(tr[128]) * g_alpha[(size_t)e * H + H - 1] * ivL;
    }
    float o0 = finz(a0) + ldin(bias, dtb, lane);
    float o1 = finz(a1) + ldin(bias, dtb, lane + 64);
    if (LEAKY){ o0 = lrelu(o0); o1 = lrelu(o1); }
    g_H[(size_t)n * C + lane] = finz(o0);
    g_H[(size_t)n * C + lane + 64] = finz(o1);
    if (C > 128 && lane == 0){
        float o2 = finz(a2) + ldin(bias, dtb, 128);
        if (LEAKY) o2 = lrelu(o2);
        g_H[(size_t)n * C + 128] = finz(o2);
    }
}

// ---------------- pooling ----------------
__global__ void k_poolA(const void* __restrict__ batch){
    int wide = g_iw;
    int idx = blockIdx.x * blockDim.x + threadIdx.x;
    if (idx >= N_NODES * 128) return;
    int n = idx >> 7, c = idx & 127;
    int b = clampi(ldi(batch, wide, n), 0, N_GRAPHS - 1);
    atomicAdd(&g_gsum[b * 128 + c], finz(g_H[(size_t)n * 128 + c]));
}

__global__ void k_poolB(const void* __restrict__ batch){
    int wide = g_iw;
    int n = blockIdx.x * blockDim.x + threadIdx.x;
    if (n >= N_NODES) return;
    int b = clampi(ldi(batch, wide, n), 0, N_GRAPHS - 1);
    atomicAdd(&g_gcnt[b], 1.f);
}

// output is float32 (established r13/r14)
__global__ void k_fin(float* __restrict__ out){
    int idx = blockIdx.x * blockDim.x + threadIdx.x;
    if (idx >= N_GRAPHS * 128) return;
    int b = idx >> 7, c = idx & 127;
    out[b * 256 + c] = finz(finz(g_gsum[idx]) / fmaxf(g_gcnt[b], 1.f));
}

// ---------------- location-encoder MLP: fast two-stage (LDS) ----------------
__global__ void k_loc(const void* __restrict__ loc, const void* __restrict__ Wl1,
                      const void* __restrict__ bl1, const void* __restrict__ Wl2,
                      const void* __restrict__ bl2, float* __restrict__ out){
    int dtl = g_dt[1], dtw1 = g_dt[16], dtb1 = g_dt[17], dtw2 = g_dt[18], dtb2 = g_dt[19];
    int b = blockIdx.x, t = threadIdx.x;   // 64 blocks x 256 threads
    __shared__ float hs[256];
    float w0 = ldin(Wl1, dtw1, t);
    float w1 = ldin(Wl1, dtw1, 256 + t);
    float bb = ldin(bl1, dtb1, t);
    float s = 0.f;
    #pragma unroll 5
    for (int l = 0; l < N_LOCS; l++){
        float x0 = ldin(loc, dtl, ((size_t)b * N_LOCS + l) * 2);
        float x1 = ldin(loc, dtl, ((size_t)b * N_LOCS + l) * 2 + 1);
        s += tanhf(x0 * w0 + x1 * w1 + bb);
    }
    hs[t] = s;
    __syncthreads();
    if (t < 128){
        float acc = 0.f;
        #pragma unroll 8
        for (int j = 0; j < 256; j++) acc += hs[j] * ldin(Wl2, dtw2, (size_t)j * 128 + t);
        out[(size_t)b * 256 + 128 + t] = finz(acc * (1.f / (float)N_LOCS) + ldin(bl2, dtb2, t));
    }
}

// ---------------- per-layer driver ----------------
template<int H, int O, int C, bool LEAKY>
static void gat_layer(const void* ei, const void* as, const void* ad, const void* bias,
                      int s_as, int s_ad, int s_b, hipStream_t stream){
    const int EB  = (E_TOT + 255) / 256;
    const int NH  = (N_NODES * H + 255) / 256;
    const int GB  = (N_NODES + 3) / 4;          // one wave per node
    k_esed<H, O, C><<<NH, 256, 0, stream>>>(as, ad, s_as, s_ad);
    k_zero_layer<H><<<NH, 256, 0, stream>>>();
    k_emax<H><<<EB, 256, 0, stream>>>(ei);
    k_mfin<H><<<NH, 256, 0, stream>>>();
    k_esum<H><<<EB, 256, 0, stream>>>(ei);
    k_gather<H, O, C, LEAKY><<<GB, 256, 0, stream>>>(bias, s_b);
}

// ---------------- launch ----------------
extern "C" void kernel_launch(void* const* d_in, const int* in_sizes, int n_in,
                              void* d_out, int out_size, void* d_ws, size_t ws_size,
                              hipStream_t stream){
    static const int want[20] = {300000, 6400, 1600000, 50000,
                                 774, 129, 129, 129,
                                 16641, 129, 129, 129,
                                 16512, 128, 128, 128,
                                 512, 256, 32768, 128};
    const void* P[20];
    bool assigned[20];
    for (int s = 0; s < 20; s++){ P[s] = nullptr; assigned[s] = false; }
    bool ok = (n_in == 20);
    if (ok){
        for (int i = 0; i < 20; i++){
            int sz = in_sizes[i], hit = -1;
            for (int s = 0; s < 20; s++)
                if (!assigned[s] && want[s] == sz){ hit = s; break; }
            if (hit < 0){ ok = false; break; }
            P[hit] = d_in[i]; assigned[hit] = true;
        }
        for (int s = 0; s < 20 && ok; s++) if (!assigned[s]) ok = false;
    }
    if (!ok) for (int s = 0; s < 20 && s < n_in; s++) P[s] = d_in[s];

    const void* x    = P[0];
    const void* loc  = P[1];
    const void* ei   = P[2];
    const void* batch= P[3];
    const void* W0   = P[4];
    const void* as0  = P[5];
    const void* ad0  = P[6];
    const void* b0   = P[7];
    const void* W1   = P[8];
    const void* as1  = P[9];
    const void* ad1  = P[10];
    const void* b1   = P[11];
    const void* W2   = P[12];
    const void* as2  = P[13];
    const void* ad2  = P[14];
    const void* b2   = P[15];
    const void* Wl1  = P[16];
    const void* bl1  = P[17];
    const void* Wl2  = P[18];
    const void* bl2  = P[19];
    float* out = (float*)d_out;
    (void)d_ws; (void)ws_size; (void)out_size;

    const int EB = (E_TOT + 255) / 256;
    k_detect<<<1, 64, 0, stream>>>(x, loc, W0, as0, ad0, W1, as1, ad1, W2, as2, ad2, Wl1, Wl2, ei);
    k_zero_global<<<(N_NODES + 255) / 256, 256, 0, stream>>>();

    // CSR build (graph shared by all 3 layers) — parallel 3-stage scan
    k_deg    <<<EB, 256, 0, stream>>>(ei);
    k_scan1  <<<SCAN_B, 256, 0, stream>>>();
    k_scan2  <<<1, 64, 0, stream>>>();
    k_scan3  <<<SCAN_B, 256, 0, stream>>>();
    k_fillcsr<<<EB, 256, 0, stream>>>(ei);

    // layer 0
    k_gemm0<<<(N_NODES * 129 + 255) / 256, 256, 0, stream>>>(x, W0);
    gat_layer<3, 43, 129, true>(ei, as0, ad0, b0, 5, 6, 7, stream);

    // layer 1
    k_gemm<129, 129><<<(N_NODES * 129 + 255) / 256, 256, 0, stream>>>(W1, 8);
    gat_layer<3, 43, 129, true>(ei, as1, ad1, b1, 9, 10, 11, stream);

    // layer 2
    k_gemm<129, 128><<<(N_NODES * 128 + 255) / 256, 256, 0, stream>>>(W2, 12);
    gat_layer<1, 128, 128, false>(ei, as2, ad2, b2, 13, 14, 15, stream);

    // pooling + output (f32 stores)
    k_poolA<<<(N_NODES * 128 + 255) / 256, 256, 0, stream>>>(batch);
    k_poolB<<<(N_NODES + 255) / 256, 256, 0, stream>>>(batch);
    k_fin  <<<(N_GRAPHS * 128 + 255) / 256, 256, 0, stream>>>(out);
    k_loc  <<<N_GRAPHS, 256, 0, stream>>>(loc, Wl1, bl1, Wl2, bl2, out);
}

// Round 18
// 1850.588 us; speedup vs baseline: 3.3669x; 1.2314x over previous
//
#include <hip/hip_runtime.h>
#include <hip/hip_bf16.h>
#include <math.h>

#define N_NODES  50000
#define N_EDGES  800000
#define E_TOT    850000   /* edges + self loops */
#define N_GRAPHS 64
#define N_LOCS   50
#define SCAN_B   ((N_NODES + 255) / 256)   /* 196 scan blocks */

typedef __hip_bfloat16 bf16;

// ---------------- static scratch ----------------
__device__ int      g_dt[20];                    // float inputs: 0=bf16, 1=f32, 2=f64
__device__ int      g_iw;                        // int inputs: 1 = int64, 0 = int32
__device__ int      g_deg[N_NODES];
__device__ int      g_cursor[N_NODES];
__device__ int      g_rowptr[N_NODES + 1];
__device__ int      g_bsum[SCAN_B];
__device__ int      g_csrc[E_TOT];               // CSR: src node per slot
__device__ int      g_cedge[E_TOT];              // CSR: edge id per slot (alpha index)
__device__ float    g_Wp[129 * 132];             // padded f32 weight for current layer
__device__ float    g_T[(size_t)N_NODES * 129];  // transformed features (this layer)
__device__ float    g_H[(size_t)N_NODES * 129];  // layer output (next layer input)
__device__ float    g_es[N_NODES * 3];
__device__ float    g_ed[N_NODES * 3];
__device__ unsigned g_mkey[N_NODES * 3];         // segment-max keys
__device__ float    g_m[N_NODES * 3];            // segment max (finite, 0 if empty)
__device__ float    g_z[N_NODES * 3];            // exp-sum
__device__ float    g_alpha[(size_t)E_TOT * 3];  // unnormalized exp weights per edge/head
__device__ float    g_gsum[N_GRAPHS * 128];
__device__ float    g_gcnt[N_GRAPHS];

// ---------------- helpers ----------------
__device__ __forceinline__ float b2f(bf16 x){ return __bfloat162float(x); }
__device__ __forceinline__ float lrelu(float x){ return x > 0.f ? x : 0.2f * x; }
__device__ __forceinline__ int   clampi(int v, int lo, int hi){ return v < lo ? lo : (v > hi ? hi : v); }
__device__ __forceinline__ float finz(float v){
    unsigned u = __float_as_uint(v);
    return ((u & 0x7F800000u) == 0x7F800000u) ? 0.f : v;   // NaN/inf -> 0
}
// dtype-dispatching sanitized float input load: 0=bf16, 1=f32, 2=f64
__device__ __forceinline__ float ldin(const void* p, int m, size_t i){
    float v = (m == 2) ? (float)((const double*)p)[i]
            : (m == 1) ? ((const float*)p)[i]
            :            b2f(((const bf16*)p)[i]);
    return finz(v);
}
__device__ __forceinline__ int ldi(const void* p, int wide, size_t i){
    return wide ? (int)((const long long*)p)[i] : ((const int*)p)[i];
}
__device__ __forceinline__ float expc(float a){ return __expf(fminf(fmaxf(a, -80.f), 0.f)); }
// order-preserving float<->unsigned key (0 reserved as "empty" sentinel)
__device__ __forceinline__ unsigned fkey(float f){
    unsigned u = __float_as_uint(f);
    return (u & 0x80000000u) ? ~u : (u | 0x80000000u);
}
__device__ __forceinline__ float kinv(unsigned k){
    return __uint_as_float((k & 0x80000000u) ? (k ^ 0x80000000u) : ~k);
}
// edge -> (src,dst) including self-loops
__device__ __forceinline__ void edge_sd(const void* ei, int wide, int e, int& src, int& dst){
    if (e < N_EDGES){
        src = clampi(ldi(ei, wide, e), 0, N_NODES - 1);
        dst = clampi(ldi(ei, wide, (size_t)N_EDGES + e), 0, N_NODES - 1);
    } else {
        src = dst = e - N_EDGES;
    }
}

// ---------------- dtype detection (1 wave) ----------------
__global__ void k_detect(const void* x, const void* loc, const void* W0,
                         const void* as0, const void* ad0, const void* W1,
                         const void* as1, const void* ad1, const void* W2,
                         const void* as2, const void* ad2, const void* Wl1,
                         const void* Wl2, const void* ei){
    const void* ps[13] = {x, loc, W0, as0, ad0, W1, as1, ad1, W2, as2, ad2, Wl1, Wl2};
    const int  sl[13]  = {0,  1,   4,  5,   6,   8,  9,   10,  12, 13,  14,  16,  18};
    int lane = threadIdx.x;   // 64 lanes
    for (int t = 0; t < 13; t++){
        float vf = ((const float*)ps[t])[lane];
        unsigned uf = __float_as_uint(vf);
        bool hit64 = ((uf & 0x7F800000u) == 0x7F800000u) || fabsf(vf) > 1e4f;
        int n64 = __popcll(__ballot(hit64));

        float vb = b2f(((const bf16*)ps[t])[lane]);
        unsigned ub = __float_as_uint(vb);
        bool hit32 = ((ub & 0x7F800000u) == 0x7F800000u) || fabsf(vb) > 1e4f;
        int n32 = __popcll(__ballot(hit32));

        if (lane == 0) g_dt[sl[t]] = (n64 >= 2) ? 2 : ((n32 >= 2) ? 1 : 0);
    }
    int w0 = ((const int*)ei)[lane];
    unsigned long long zm = __ballot((lane & 1) && (w0 == 0));
    if (lane == 0){
        g_iw = (__popcll(zm) >= 16) ? 1 : 0;
        g_dt[2] = g_dt[3] = 0;
        g_dt[7] = g_dt[11] = g_dt[15] = 0;
        g_dt[17] = g_dt[19] = 0;
    }
}

// ---------------- zero init ----------------
__global__ void k_zero_global(){
    int i = blockIdx.x * blockDim.x + threadIdx.x;
    if (i < N_NODES) g_deg[i] = 0;
    if (i < N_GRAPHS * 128) g_gsum[i] = 0.f;
    if (i < N_GRAPHS) g_gcnt[i] = 0.f;
}
template<int H>
__global__ void k_zero_layer(){
    int i = blockIdx.x * blockDim.x + threadIdx.x;
    if (i < N_NODES * H){ g_mkey[i] = 0u; g_z[i] = 0.f; }
}

// ---------------- CSR build (once per call) ----------------
__global__ void k_deg(const void* __restrict__ ei){
    int wide = g_iw;
    int e = blockIdx.x * blockDim.x + threadIdx.x;
    if (e >= E_TOT) return;
    int src, dst; edge_sd(ei, wide, e, src, dst);
    atomicAdd(&g_deg[dst], 1);
}

// 3-stage parallel exclusive scan of g_deg -> g_rowptr/g_cursor
__global__ void k_scan1(){   // per-block inclusive scan (LDS), emit block sum
    __shared__ int s[256];
    int i = blockIdx.x * 256 + threadIdx.x;
    int v = (i < N_NODES) ? g_deg[i] : 0;
    s[threadIdx.x] = v;
    __syncthreads();
    for (int off = 1; off < 256; off <<= 1){
        int add = (threadIdx.x >= off) ? s[threadIdx.x - off] : 0;
        __syncthreads();
        s[threadIdx.x] += add;
        __syncthreads();
    }
    if (threadIdx.x == 255) g_bsum[blockIdx.x] = s[255];
    if (i < N_NODES) g_rowptr[i] = s[threadIdx.x] - v;   // intra-block exclusive
}

__global__ void k_scan2(){   // 1 wave scans the 196 block sums (exclusive)
    int lane = threadIdx.x;
    int carry = 0;
    for (int base = 0; base < SCAN_B; base += 64){
        int i = base + lane;
        int v = (i < SCAN_B) ? g_bsum[i] : 0;
        int s = v;
        #pragma unroll
        for (int off = 1; off < 64; off <<= 1){
            int t = __shfl_up(s, off);
            if (lane >= off) s += t;
        }
        if (i < SCAN_B) g_bsum[i] = carry + s - v;
        carry += __shfl(s, 63);
    }
    if (lane == 0) g_rowptr[N_NODES] = carry;   // == E_TOT
}

__global__ void k_scan3(){   // add block offsets
    int i = blockIdx.x * 256 + threadIdx.x;
    if (i < N_NODES){
        int r = g_rowptr[i] + g_bsum[blockIdx.x];
        g_rowptr[i] = r;
        g_cursor[i] = r;
    }
}

__global__ void k_fillcsr(const void* __restrict__ ei){
    int wide = g_iw;
    int e = blockIdx.x * blockDim.x + threadIdx.x;
    if (e >= E_TOT) return;
    int src, dst; edge_sd(ei, wide, e, src, dst);
    int pos = atomicAdd(&g_cursor[dst], 1);
    if (pos >= 0 && pos < E_TOT){ g_csrc[pos] = src; g_cedge[pos] = e; }
}

// ---------------- GEMMs ----------------
__global__ void k_gemm0(const void* __restrict__ x, const void* __restrict__ W){
    int dtx = g_dt[0], dtw = g_dt[4];
    int idx = blockIdx.x * blockDim.x + threadIdx.x;
    if (idx >= N_NODES * 129) return;
    int n = idx / 129, c = idx - n * 129;
    float acc = 0.f;
    #pragma unroll
    for (int k = 0; k < 6; k++)
        acc += ldin(x, dtx, (size_t)n * 6 + k) * ldin(W, dtw, k * 129 + c);
    g_T[idx] = finz(acc);
}

// pad/convert W [K][CO] -> g_Wp [K][132] (f32, sanitized) — once per layer
template<int K, int CO>
__global__ void k_prepW(const void* __restrict__ W, int slot){
    int m = g_dt[slot];
    int idx = blockIdx.x * blockDim.x + threadIdx.x;
    if (idx >= K * 132) return;
    int k = idx / 132, c = idx - k * 132;
    g_Wp[idx] = (c < CO) ? ldin(W, m, (size_t)k * CO + c) : 0.f;
}

// vectorized GEMM: g_T[n][c] = sum_k g_H[n][k] * Wp[k][c]
// block: 256 threads = 8 rows x 32 col-groups; thread -> 4 adjacent cols (float4)
template<int K, int CO>
__global__ __launch_bounds__(256)
void k_gemmf(){
    int tid = threadIdx.x;
    int n = blockIdx.x * 8 + (tid >> 5);
    int g = tid & 31;
    if (n >= N_NODES) return;
    const float* ar = g_H + (size_t)n * K;
    const float4* wp = (const float4*)g_Wp;   // [K][33] float4s
    float4 acc = make_float4(0.f, 0.f, 0.f, 0.f);
    float accE = 0.f;
    #pragma unroll 4
    for (int k = 0; k < K; k++){
        float a = ar[k];                      // 32 lanes same addr -> broadcast
        float4 w = wp[k * 33 + g];            // aligned 16B, coalesced
        acc.x += a * w.x; acc.y += a * w.y;
        acc.z += a * w.z; acc.w += a * w.w;
        if (CO > 128 && g == 0) accE += a * g_Wp[k * 132 + 128];
    }
    float* tr = g_T + (size_t)n * CO;
    int c = 4 * g;
    tr[c] = acc.x; tr[c + 1] = acc.y; tr[c + 2] = acc.z; tr[c + 3] = acc.w;
    if (CO > 128 && g == 0) tr[128] = accE;
}

// ---------------- per-node attention coefficients ----------------
template<int H, int O, int C>
__global__ void k_esed(const void* __restrict__ as, const void* __restrict__ ad,
                       int slot_as, int slot_ad){
    int dta = g_dt[slot_as], dtd = g_dt[slot_ad];
    int idx = blockIdx.x * blockDim.x + threadIdx.x;
    if (idx >= N_NODES * H) return;
    int n = idx / H, h = idx - n * H;
    const float* tr = g_T + (size_t)n * C + h * O;
    float a = 0.f, b = 0.f;
    #pragma unroll 4
    for (int o = 0; o < O; o++){
        float v = finz(tr[o]);
        a += v * ldin(as, dta, h * O + o);
        b += v * ldin(ad, dtd, h * O + o);
    }
    g_es[idx] = finz(a); g_ed[idx] = finz(b);
}

// ---------------- edge-parallel softmax stats (atomic, validated) ----------
template<int H>
__global__ void k_emax(const void* __restrict__ ei){
    int wide = g_iw;
    int e = blockIdx.x * blockDim.x + threadIdx.x;
    if (e >= E_TOT) return;
    int src, dst; edge_sd(ei, wide, e, src, dst);
    #pragma unroll
    for (int h = 0; h < H; h++){
        float val = lrelu(finz(g_es[src * H + h]) + finz(g_ed[dst * H + h]));
        atomicMax(&g_mkey[dst * H + h], fkey(val));
    }
}

template<int H>
__global__ void k_mfin(){
    int idx = blockIdx.x * blockDim.x + threadIdx.x;
    if (idx >= N_NODES * H) return;
    unsigned k = g_mkey[idx];
    g_m[idx] = (k == 0u) ? 0.f : finz(kinv(k));
}

template<int H>
__global__ void k_esum(const void* __restrict__ ei){
    int wide = g_iw;
    int e = blockIdx.x * blockDim.x + threadIdx.x;
    if (e >= E_TOT) return;
    int src, dst; edge_sd(ei, wide, e, src, dst);
    #pragma unroll
    for (int h = 0; h < H; h++){
        float val = lrelu(finz(g_es[src * H + h]) + finz(g_ed[dst * H + h]));
        float w = expc(val - g_m[dst * H + h]);
        g_alpha[(size_t)e * H + h] = w;
        atomicAdd(&g_z[dst * H + h], w);
    }
}

// ---------------- CSR gather: one wave per dst node, no atomics -------------
template<int H, int O, int C, bool LEAKY>
__global__ __launch_bounds__(256)
void k_gather(const void* __restrict__ bias, int slot_b){
    int dtb = g_dt[slot_b];
    int wv = threadIdx.x >> 6, lane = threadIdx.x & 63;
    int n = blockIdx.x * 4 + wv;
    if (n >= N_NODES) return;
    int r0 = clampi(g_rowptr[n], 0, E_TOT);
    int r1 = clampi(g_rowptr[n + 1], r0, E_TOT);

    float inv[H];
    #pragma unroll
    for (int h = 0; h < H; h++) inv[h] = 1.f / (finz(g_z[n * H + h]) + 1e-16f);

    const int h0 = lane / O;
    const int h1 = (lane + 64) / O;
    float iv0 = inv[h0], iv1 = inv[h1], ivL = inv[H - 1];
    float a0 = 0.f, a1 = 0.f, a2 = 0.f;
    for (int i = r0; i < r1; i++){
        int src = clampi(g_csrc[i], 0, N_NODES - 1);
        int e   = clampi(g_cedge[i], 0, E_TOT - 1);
        const float* tr = g_T + (size_t)src * C;
        float w0 = g_alpha[(size_t)e * H + h0] * iv0;
        float w1 = g_alpha[(size_t)e * H + h1] * iv1;
        a0 += finz(tr[lane]) * w0;
        a1 += finz(tr[lane + 64]) * w1;
        if (C > 128 && lane == 0)
            a2 += finz(tr[128]) * g_alpha[(size_t)e * H + H - 1] * ivL;
    }
    float o0 = finz(a0) + ldin(bias, dtb, lane);
    float o1 = finz(a1) + ldin(bias, dtb, lane + 64);
    if (LEAKY){ o0 = lrelu(o0); o1 = lrelu(o1); }
    g_H[(size_t)n * C + lane] = finz(o0);
    g_H[(size_t)n * C + lane + 64] = finz(o1);
    if (C > 128 && lane == 0){
        float o2 = finz(a2) + ldin(bias, dtb, 128);
        if (LEAKY) o2 = lrelu(o2);
        g_H[(size_t)n * C + 128] = finz(o2);
    }
}

// ---------------- pooling ----------------
__global__ void k_poolA(const void* __restrict__ batch){
    int wide = g_iw;
    int idx = blockIdx.x * blockDim.x + threadIdx.x;
    if (idx >= N_NODES * 128) return;
    int n = idx >> 7, c = idx & 127;
    int b = clampi(ldi(batch, wide, n), 0, N_GRAPHS - 1);
    atomicAdd(&g_gsum[b * 128 + c], finz(g_H[(size_t)n * 128 + c]));
}

__global__ void k_poolB(const void* __restrict__ batch){
    int wide = g_iw;
    int n = blockIdx.x * blockDim.x + threadIdx.x;
    if (n >= N_NODES) return;
    int b = clampi(ldi(batch, wide, n), 0, N_GRAPHS - 1);
    atomicAdd(&g_gcnt[b], 1.f);
}

// output is float32 (established r13/r14)
__global__ void k_fin(float* __restrict__ out){
    int idx = blockIdx.x * blockDim.x + threadIdx.x;
    if (idx >= N_GRAPHS * 128) return;
    int b = idx >> 7, c = idx & 127;
    out[b * 256 + c] = finz(finz(g_gsum[idx]) / fmaxf(g_gcnt[b], 1.f));
}

// ---------------- location-encoder MLP: fast two-stage (LDS) ----------------
__global__ void k_loc(const void* __restrict__ loc, const void* __restrict__ Wl1,
                      const void* __restrict__ bl1, const void* __restrict__ Wl2,
                      const void* __restrict__ bl2, float* __restrict__ out){
    int dtl = g_dt[1], dtw1 = g_dt[16], dtb1 = g_dt[17], dtw2 = g_dt[18], dtb2 = g_dt[19];
    int b = blockIdx.x, t = threadIdx.x;   // 64 blocks x 256 threads
    __shared__ float hs[256];
    float w0 = ldin(Wl1, dtw1, t);
    float w1 = ldin(Wl1, dtw1, 256 + t);
    float bb = ldin(bl1, dtb1, t);
    float s = 0.f;
    #pragma unroll 5
    for (int l = 0; l < N_LOCS; l++){
        float x0 = ldin(loc, dtl, ((size_t)b * N_LOCS + l) * 2);
        float x1 = ldin(loc, dtl, ((size_t)b * N_LOCS + l) * 2 + 1);
        s += tanhf(x0 * w0 + x1 * w1 + bb);
    }
    hs[t] = s;
    __syncthreads();
    if (t < 128){
        float acc = 0.f;
        #pragma unroll 8
        for (int j = 0; j < 256; j++) acc += hs[j] * ldin(Wl2, dtw2, (size_t)j * 128 + t);
        out[(size_t)b * 256 + 128 + t] = finz(acc * (1.f / (float)N_LOCS) + ldin(bl2, dtb2, t));
    }
}

// ---------------- per-layer driver ----------------
template<int H, int O, int C, bool LEAKY>
static void gat_layer(const void* ei, const void* as, const void* ad, const void* bias,
                      int s_as, int s_ad, int s_b, hipStream_t stream){
    const int EB  = (E_TOT + 255) / 256;
    const int NH  = (N_NODES * H + 255) / 256;
    const int GB  = (N_NODES + 3) / 4;          // one wave per node
    k_esed<H, O, C><<<NH, 256, 0, stream>>>(as, ad, s_as, s_ad);
    k_zero_layer<H><<<NH, 256, 0, stream>>>();
    k_emax<H><<<EB, 256, 0, stream>>>(ei);
    k_mfin<H><<<NH, 256, 0, stream>>>();
    k_esum<H><<<EB, 256, 0, stream>>>(ei);
    k_gather<H, O, C, LEAKY><<<GB, 256, 0, stream>>>(bias, s_b);
}

// ---------------- launch ----------------
extern "C" void kernel_launch(void* const* d_in, const int* in_sizes, int n_in,
                              void* d_out, int out_size, void* d_ws, size_t ws_size,
                              hipStream_t stream){
    static const int want[20] = {300000, 6400, 1600000, 50000,
                                 774, 129, 129, 129,
                                 16641, 129, 129, 129,
                                 16512, 128, 128, 128,
                                 512, 256, 32768, 128};
    const void* P[20];
    bool assigned[20];
    for (int s = 0; s < 20; s++){ P[s] = nullptr; assigned[s] = false; }
    bool ok = (n_in == 20);
    if (ok){
        for (int i = 0; i < 20; i++){
            int sz = in_sizes[i], hit = -1;
            for (int s = 0; s < 20; s++)
                if (!assigned[s] && want[s] == sz){ hit = s; break; }
            if (hit < 0){ ok = false; break; }
            P[hit] = d_in[i]; assigned[hit] = true;
        }
        for (int s = 0; s < 20 && ok; s++) if (!assigned[s]) ok = false;
    }
    if (!ok) for (int s = 0; s < 20 && s < n_in; s++) P[s] = d_in[s];

    const void* x    = P[0];
    const void* loc  = P[1];
    const void* ei   = P[2];
    const void* batch= P[3];
    const void* W0   = P[4];
    const void* as0  = P[5];
    const void* ad0  = P[6];
    const void* b0   = P[7];
    const void* W1   = P[8];
    const void* as1  = P[9];
    const void* ad1  = P[10];
    const void* b1   = P[11];
    const void* W2   = P[12];
    const void* as2  = P[13];
    const void* ad2  = P[14];
    const void* b2   = P[15];
    const void* Wl1  = P[16];
    const void* bl1  = P[17];
    const void* Wl2  = P[18];
    const void* bl2  = P[19];
    float* out = (float*)d_out;
    (void)d_ws; (void)ws_size; (void)out_size;

    const int EB = (E_TOT + 255) / 256;
    const int GEMM_B = (N_NODES + 7) / 8;
    k_detect<<<1, 64, 0, stream>>>(x, loc, W0, as0, ad0, W1, as1, ad1, W2, as2, ad2, Wl1, Wl2, ei);
    k_zero_global<<<(N_NODES + 255) / 256, 256, 0, stream>>>();

    // CSR build (graph shared by all 3 layers) — parallel 3-stage scan
    k_deg    <<<EB, 256, 0, stream>>>(ei);
    k_scan1  <<<SCAN_B, 256, 0, stream>>>();
    k_scan2  <<<1, 64, 0, stream>>>();
    k_scan3  <<<SCAN_B, 256, 0, stream>>>();
    k_fillcsr<<<EB, 256, 0, stream>>>(ei);

    // layer 0
    k_gemm0<<<(N_NODES * 129 + 255) / 256, 256, 0, stream>>>(x, W0);
    gat_layer<3, 43, 129, true>(ei, as0, ad0, b0, 5, 6, 7, stream);

    // layer 1
    k_prepW<129, 129><<<(129 * 132 + 255) / 256, 256, 0, stream>>>(W1, 8);
    k_gemmf<129, 129><<<GEMM_B, 256, 0, stream>>>();
    gat_layer<3, 43, 129, true>(ei, as1, ad1, b1, 9, 10, 11, stream);

    // layer 2
    k_prepW<129, 128><<<(129 * 132 + 255) / 256, 256, 0, stream>>>(W2, 12);
    k_gemmf<129, 128><<<GEMM_B, 256, 0, stream>>>();
    gat_layer<1, 128, 128, false>(ei, as2, ad2, b2, 13, 14, 15, stream);

    // pooling + output (f32 stores)
    k_poolA<<<(N_NODES * 128 + 255) / 256, 256, 0, stream>>>(batch);
    k_poolB<<<(N_NODES + 255) / 256, 256, 0, stream>>>(batch);
    k_fin  <<<(N_GRAPHS * 128 + 255) / 256, 256, 0, stream>>>(out);
    k_loc  <<<N_GRAPHS, 256, 0, stream>>>(loc, Wl1, bl1, Wl2, bl2, out);
}

// Round 19
// 1594.251 us; speedup vs baseline: 3.9083x; 1.1608x over previous
//
#include <hip/hip_runtime.h>
#include <hip/hip_bf16.h>
#include <math.h>

#define N_NODES  50000
#define N_EDGES  800000
#define E_TOT    850000   /* edges + self loops */
#define N_GRAPHS 64
#define N_LOCS   50
#define SCAN_B   ((N_NODES + 255) / 256)   /* 196 scan blocks */

typedef __hip_bfloat16 bf16;

// ---------------- static scratch ----------------
__device__ int      g_dt[20];                    // float inputs: 0=bf16, 1=f32, 2=f64
__device__ int      g_iw;                        // int inputs: 1 = int64, 0 = int32
__device__ int      g_deg[N_NODES];
__device__ int      g_cursor[N_NODES];
__device__ int      g_rowptr[N_NODES + 1];
__device__ int      g_bsum[SCAN_B];
__device__ int      g_csrc[E_TOT];               // CSR: src node per slot
__device__ int      g_cedge[E_TOT];              // CSR: edge id per slot (alpha index)
__device__ float    g_Wp[129 * 132];             // padded f32 weight for current layer
__device__ float    g_T[(size_t)N_NODES * 129];  // transformed features (this layer)
__device__ float    g_H[(size_t)N_NODES * 129];  // layer output (next layer input)
__device__ float    g_es[N_NODES * 3];
__device__ float    g_ed[N_NODES * 3];
__device__ unsigned g_mkey[N_NODES * 3];         // segment-max keys
__device__ float    g_m[N_NODES * 3];            // segment max (finite, 0 if empty)
__device__ float    g_z[N_NODES * 3];            // exp-sum
__device__ float    g_alpha[(size_t)E_TOT * 3];  // unnormalized exp weights per edge/head
__device__ float    g_gsum[N_GRAPHS * 128];
__device__ float    g_gcnt[N_GRAPHS];

// ---------------- helpers ----------------
__device__ __forceinline__ float b2f(bf16 x){ return __bfloat162float(x); }
__device__ __forceinline__ float lrelu(float x){ return x > 0.f ? x : 0.2f * x; }
__device__ __forceinline__ int   clampi(int v, int lo, int hi){ return v < lo ? lo : (v > hi ? hi : v); }
__device__ __forceinline__ float finz(float v){
    unsigned u = __float_as_uint(v);
    return ((u & 0x7F800000u) == 0x7F800000u) ? 0.f : v;   // NaN/inf -> 0
}
// dtype-dispatching sanitized float input load: 0=bf16, 1=f32, 2=f64
__device__ __forceinline__ float ldin(const void* p, int m, size_t i){
    float v = (m == 2) ? (float)((const double*)p)[i]
            : (m == 1) ? ((const float*)p)[i]
            :            b2f(((const bf16*)p)[i]);
    return finz(v);
}
__device__ __forceinline__ int ldi(const void* p, int wide, size_t i){
    return wide ? (int)((const long long*)p)[i] : ((const int*)p)[i];
}
__device__ __forceinline__ float expc(float a){ return __expf(fminf(fmaxf(a, -80.f), 0.f)); }
// order-preserving float<->unsigned key (0 reserved as "empty" sentinel)
__device__ __forceinline__ unsigned fkey(float f){
    unsigned u = __float_as_uint(f);
    return (u & 0x80000000u) ? ~u : (u | 0x80000000u);
}
__device__ __forceinline__ float kinv(unsigned k){
    return __uint_as_float((k & 0x80000000u) ? (k ^ 0x80000000u) : ~k);
}
// edge -> (src,dst) including self-loops
__device__ __forceinline__ void edge_sd(const void* ei, int wide, int e, int& src, int& dst){
    if (e < N_EDGES){
        src = clampi(ldi(ei, wide, e), 0, N_NODES - 1);
        dst = clampi(ldi(ei, wide, (size_t)N_EDGES + e), 0, N_NODES - 1);
    } else {
        src = dst = e - N_EDGES;
    }
}

// ---------------- dtype detection (1 wave) ----------------
__global__ void k_detect(const void* x, const void* loc, const void* W0,
                         const void* as0, const void* ad0, const void* W1,
                         const void* as1, const void* ad1, const void* W2,
                         const void* as2, const void* ad2, const void* Wl1,
                         const void* Wl2, const void* ei){
    const void* ps[13] = {x, loc, W0, as0, ad0, W1, as1, ad1, W2, as2, ad2, Wl1, Wl2};
    const int  sl[13]  = {0,  1,   4,  5,   6,   8,  9,   10,  12, 13,  14,  16,  18};
    int lane = threadIdx.x;   // 64 lanes
    for (int t = 0; t < 13; t++){
        float vf = ((const float*)ps[t])[lane];
        unsigned uf = __float_as_uint(vf);
        bool hit64 = ((uf & 0x7F800000u) == 0x7F800000u) || fabsf(vf) > 1e4f;
        int n64 = __popcll(__ballot(hit64));

        float vb = b2f(((const bf16*)ps[t])[lane]);
        unsigned ub = __float_as_uint(vb);
        bool hit32 = ((ub & 0x7F800000u) == 0x7F800000u) || fabsf(vb) > 1e4f;
        int n32 = __popcll(__ballot(hit32));

        if (lane == 0) g_dt[sl[t]] = (n64 >= 2) ? 2 : ((n32 >= 2) ? 1 : 0);
    }
    int w0 = ((const int*)ei)[lane];
    unsigned long long zm = __ballot((lane & 1) && (w0 == 0));
    if (lane == 0){
        g_iw = (__popcll(zm) >= 16) ? 1 : 0;
        g_dt[2] = g_dt[3] = 0;
        g_dt[7] = g_dt[11] = g_dt[15] = 0;
        g_dt[17] = g_dt[19] = 0;
    }
}

// ---------------- zero init ----------------
__global__ void k_zero_global(){
    int i = blockIdx.x * blockDim.x + threadIdx.x;
    if (i < N_NODES) g_deg[i] = 0;
    if (i < N_GRAPHS * 128) g_gsum[i] = 0.f;
}
template<int H>
__global__ void k_zero_layer(){
    int i = blockIdx.x * blockDim.x + threadIdx.x;
    if (i < N_NODES * H){ g_mkey[i] = 0u; g_z[i] = 0.f; }
}

// ---------------- CSR build (once per call) ----------------
__global__ void k_deg(const void* __restrict__ ei){
    int wide = g_iw;
    int e = blockIdx.x * blockDim.x + threadIdx.x;
    if (e >= E_TOT) return;
    int src, dst; edge_sd(ei, wide, e, src, dst);
    atomicAdd(&g_deg[dst], 1);
}

// 3-stage parallel exclusive scan of g_deg -> g_rowptr/g_cursor
__global__ void k_scan1(){   // per-block inclusive scan (LDS), emit block sum
    __shared__ int s[256];
    int i = blockIdx.x * 256 + threadIdx.x;
    int v = (i < N_NODES) ? g_deg[i] : 0;
    s[threadIdx.x] = v;
    __syncthreads();
    for (int off = 1; off < 256; off <<= 1){
        int add = (threadIdx.x >= off) ? s[threadIdx.x - off] : 0;
        __syncthreads();
        s[threadIdx.x] += add;
        __syncthreads();
    }
    if (threadIdx.x == 255) g_bsum[blockIdx.x] = s[255];
    if (i < N_NODES) g_rowptr[i] = s[threadIdx.x] - v;   // intra-block exclusive
}

__global__ void k_scan2(){   // 1 wave scans the 196 block sums (exclusive)
    int lane = threadIdx.x;
    int carry = 0;
    for (int base = 0; base < SCAN_B; base += 64){
        int i = base + lane;
        int v = (i < SCAN_B) ? g_bsum[i] : 0;
        int s = v;
        #pragma unroll
        for (int off = 1; off < 64; off <<= 1){
            int t = __shfl_up(s, off);
            if (lane >= off) s += t;
        }
        if (i < SCAN_B) g_bsum[i] = carry + s - v;
        carry += __shfl(s, 63);
    }
    if (lane == 0) g_rowptr[N_NODES] = carry;   // == E_TOT
}

__global__ void k_scan3(){   // add block offsets
    int i = blockIdx.x * 256 + threadIdx.x;
    if (i < N_NODES){
        int r = g_rowptr[i] + g_bsum[blockIdx.x];
        g_rowptr[i] = r;
        g_cursor[i] = r;
    }
}

__global__ void k_fillcsr(const void* __restrict__ ei){
    int wide = g_iw;
    int e = blockIdx.x * blockDim.x + threadIdx.x;
    if (e >= E_TOT) return;
    int src, dst; edge_sd(ei, wide, e, src, dst);
    int pos = atomicAdd(&g_cursor[dst], 1);
    if (pos >= 0 && pos < E_TOT){ g_csrc[pos] = src; g_cedge[pos] = e; }
}

// ---------------- GEMMs ----------------
__global__ void k_gemm0(const void* __restrict__ x, const void* __restrict__ W){
    int dtx = g_dt[0], dtw = g_dt[4];
    int idx = blockIdx.x * blockDim.x + threadIdx.x;
    if (idx >= N_NODES * 129) return;
    int n = idx / 129, c = idx - n * 129;
    float acc = 0.f;
    #pragma unroll
    for (int k = 0; k < 6; k++)
        acc += ldin(x, dtx, (size_t)n * 6 + k) * ldin(W, dtw, k * 129 + c);
    g_T[idx] = finz(acc);
}

// pad/convert W [K][CO] -> g_Wp [K][132] (f32, sanitized) — once per layer
template<int K, int CO>
__global__ void k_prepW(const void* __restrict__ W, int slot){
    int m = g_dt[slot];
    int idx = blockIdx.x * blockDim.x + threadIdx.x;
    if (idx >= K * 132) return;
    int k = idx / 132, c = idx - k * 132;
    g_Wp[idx] = (c < CO) ? ldin(W, m, (size_t)k * CO + c) : 0.f;
}

// vectorized GEMM: g_T[n][c] = sum_k g_H[n][k] * Wp[k][c]
// block: 256 threads = 8 rows x 32 col-groups; thread -> 4 adjacent cols (float4)
template<int K, int CO>
__global__ __launch_bounds__(256)
void k_gemmf(){
    int tid = threadIdx.x;
    int n = blockIdx.x * 8 + (tid >> 5);
    int g = tid & 31;
    if (n >= N_NODES) return;
    const float* ar = g_H + (size_t)n * K;
    const float4* wp = (const float4*)g_Wp;   // [K][33] float4s
    float4 acc = make_float4(0.f, 0.f, 0.f, 0.f);
    float accE = 0.f;
    #pragma unroll 4
    for (int k = 0; k < K; k++){
        float a = ar[k];                      // 32 lanes same addr -> broadcast
        float4 w = wp[k * 33 + g];            // aligned 16B, coalesced
        acc.x += a * w.x; acc.y += a * w.y;
        acc.z += a * w.z; acc.w += a * w.w;
        if (CO > 128 && g == 0) accE += a * g_Wp[k * 132 + 128];
    }
    float* tr = g_T + (size_t)n * CO;
    int c = 4 * g;
    tr[c] = acc.x; tr[c + 1] = acc.y; tr[c + 2] = acc.z; tr[c + 3] = acc.w;
    if (CO > 128 && g == 0) tr[128] = accE;
}

// ---------------- per-node attention coefficients ----------------
template<int H, int O, int C>
__global__ void k_esed(const void* __restrict__ as, const void* __restrict__ ad,
                       int slot_as, int slot_ad){
    int dta = g_dt[slot_as], dtd = g_dt[slot_ad];
    int idx = blockIdx.x * blockDim.x + threadIdx.x;
    if (idx >= N_NODES * H) return;
    int n = idx / H, h = idx - n * H;
    const float* tr = g_T + (size_t)n * C + h * O;
    float a = 0.f, b = 0.f;
    #pragma unroll 4
    for (int o = 0; o < O; o++){
        float v = finz(tr[o]);
        a += v * ldin(as, dta, h * O + o);
        b += v * ldin(ad, dtd, h * O + o);
    }
    g_es[idx] = finz(a); g_ed[idx] = finz(b);
}

// ---------------- edge-parallel softmax stats (atomic, validated) ----------
template<int H>
__global__ void k_emax(const void* __restrict__ ei){
    int wide = g_iw;
    int e = blockIdx.x * blockDim.x + threadIdx.x;
    if (e >= E_TOT) return;
    int src, dst; edge_sd(ei, wide, e, src, dst);
    #pragma unroll
    for (int h = 0; h < H; h++){
        float val = lrelu(finz(g_es[src * H + h]) + finz(g_ed[dst * H + h]));
        atomicMax(&g_mkey[dst * H + h], fkey(val));
    }
}

template<int H>
__global__ void k_mfin(){
    int idx = blockIdx.x * blockDim.x + threadIdx.x;
    if (idx >= N_NODES * H) return;
    unsigned k = g_mkey[idx];
    g_m[idx] = (k == 0u) ? 0.f : finz(kinv(k));
}

template<int H>
__global__ void k_esum(const void* __restrict__ ei){
    int wide = g_iw;
    int e = blockIdx.x * blockDim.x + threadIdx.x;
    if (e >= E_TOT) return;
    int src, dst; edge_sd(ei, wide, e, src, dst);
    #pragma unroll
    for (int h = 0; h < H; h++){
        float val = lrelu(finz(g_es[src * H + h]) + finz(g_ed[dst * H + h]));
        float w = expc(val - g_m[dst * H + h]);
        g_alpha[(size_t)e * H + h] = w;
        atomicAdd(&g_z[dst * H + h], w);
    }
}

// ---------------- CSR gather: one wave per dst node, no atomics -------------
template<int H, int O, int C, bool LEAKY>
__global__ __launch_bounds__(256)
void k_gather(const void* __restrict__ bias, int slot_b){
    int dtb = g_dt[slot_b];
    int wv = threadIdx.x >> 6, lane = threadIdx.x & 63;
    int n = blockIdx.x * 4 + wv;
    if (n >= N_NODES) return;
    int r0 = clampi(g_rowptr[n], 0, E_TOT);
    int r1 = clampi(g_rowptr[n + 1], r0, E_TOT);

    float inv[H];
    #pragma unroll
    for (int h = 0; h < H; h++) inv[h] = 1.f / (finz(g_z[n * H + h]) + 1e-16f);

    const int h0 = lane / O;
    const int h1 = (lane + 64) / O;
    float iv0 = inv[h0], iv1 = inv[h1], ivL = inv[H - 1];
    float a0 = 0.f, a1 = 0.f, a2 = 0.f;
    for (int i = r0; i < r1; i++){
        int src = clampi(g_csrc[i], 0, N_NODES - 1);
        int e   = clampi(g_cedge[i], 0, E_TOT - 1);
        const float* tr = g_T + (size_t)src * C;
        float w0 = g_alpha[(size_t)e * H + h0] * iv0;
        float w1 = g_alpha[(size_t)e * H + h1] * iv1;
        a0 += finz(tr[lane]) * w0;
        a1 += finz(tr[lane + 64]) * w1;
        if (C > 128 && lane == 0)
            a2 += finz(tr[128]) * g_alpha[(size_t)e * H + H - 1] * ivL;
    }
    float o0 = finz(a0) + ldin(bias, dtb, lane);
    float o1 = finz(a1) + ldin(bias, dtb, lane + 64);
    if (LEAKY){ o0 = lrelu(o0); o1 = lrelu(o1); }
    g_H[(size_t)n * C + lane] = finz(o0);
    g_H[(size_t)n * C + lane + 64] = finz(o1);
    if (C > 128 && lane == 0){
        float o2 = finz(a2) + ldin(bias, dtb, 128);
        if (LEAKY) o2 = lrelu(o2);
        g_H[(size_t)n * C + 128] = finz(o2);
    }
}

// ---------------- pooling (batch is sorted by construction) ----------------
// segmented accumulation: 128 channel-threads, block walks 128 consecutive
// nodes, one atomic per (segment boundary x channel) — ~100K atomics total
__global__ void k_poolA(const void* __restrict__ batch){
    int wide = g_iw;
    int c = threadIdx.x;              // 128 channels
    int n0 = blockIdx.x * 128;
    int bprev = -1; float acc = 0.f;
    for (int j = 0; j < 128; j++){
        int n = n0 + j;
        if (n >= N_NODES) break;
        int b = clampi(ldi(batch, wide, n), 0, N_GRAPHS - 1);
        if (b != bprev){
            if (bprev >= 0) atomicAdd(&g_gsum[bprev * 128 + c], acc);
            acc = 0.f; bprev = b;
        }
        acc += finz(g_H[(size_t)n * 128 + c]);
    }
    if (bprev >= 0) atomicAdd(&g_gsum[bprev * 128 + c], acc);
}

// per-graph node count via binary search on sorted batch (no atomics)
__global__ void k_cnt(const void* __restrict__ batch){
    int wide = g_iw;
    int b = threadIdx.x;              // 64 threads
    if (b >= N_GRAPHS) return;
    int lo = 0, hi = N_NODES;
    while (lo < hi){ int mid = (lo + hi) >> 1; if (ldi(batch, wide, mid) <  b) lo = mid + 1; else hi = mid; }
    int start = lo;
    lo = 0; hi = N_NODES;
    while (lo < hi){ int mid = (lo + hi) >> 1; if (ldi(batch, wide, mid) <= b) lo = mid + 1; else hi = mid; }
    g_gcnt[b] = (float)(lo - start);
}

// output is float32 (established r13/r14)
__global__ void k_fin(float* __restrict__ out){
    int idx = blockIdx.x * blockDim.x + threadIdx.x;
    if (idx >= N_GRAPHS * 128) return;
    int b = idx >> 7, c = idx & 127;
    out[b * 256 + c] = finz(finz(g_gsum[idx]) / fmaxf(g_gcnt[b], 1.f));
}

// ---------------- location-encoder MLP: fast two-stage (LDS) ----------------
__global__ void k_loc(const void* __restrict__ loc, const void* __restrict__ Wl1,
                      const void* __restrict__ bl1, const void* __restrict__ Wl2,
                      const void* __restrict__ bl2, float* __restrict__ out){
    int dtl = g_dt[1], dtw1 = g_dt[16], dtb1 = g_dt[17], dtw2 = g_dt[18], dtb2 = g_dt[19];
    int b = blockIdx.x, t = threadIdx.x;   // 64 blocks x 256 threads
    __shared__ float hs[256];
    float w0 = ldin(Wl1, dtw1, t);
    float w1 = ldin(Wl1, dtw1, 256 + t);
    float bb = ldin(bl1, dtb1, t);
    float s = 0.f;
    #pragma unroll 5
    for (int l = 0; l < N_LOCS; l++){
        float x0 = ldin(loc, dtl, ((size_t)b * N_LOCS + l) * 2);
        float x1 = ldin(loc, dtl, ((size_t)b * N_LOCS + l) * 2 + 1);
        s += tanhf(x0 * w0 + x1 * w1 + bb);
    }
    hs[t] = s;
    __syncthreads();
    if (t < 128){
        float acc = 0.f;
        #pragma unroll 8
        for (int j = 0; j < 256; j++) acc += hs[j] * ldin(Wl2, dtw2, (size_t)j * 128 + t);
        out[(size_t)b * 256 + 128 + t] = finz(acc * (1.f / (float)N_LOCS) + ldin(bl2, dtb2, t));
    }
}

// ---------------- per-layer driver ----------------
template<int H, int O, int C, bool LEAKY>
static void gat_layer(const void* ei, const void* as, const void* ad, const void* bias,
                      int s_as, int s_ad, int s_b, hipStream_t stream){
    const int EB  = (E_TOT + 255) / 256;
    const int NH  = (N_NODES * H + 255) / 256;
    const int GB  = (N_NODES + 3) / 4;          // one wave per node
    k_esed<H, O, C><<<NH, 256, 0, stream>>>(as, ad, s_as, s_ad);
    k_zero_layer<H><<<NH, 256, 0, stream>>>();
    k_emax<H><<<EB, 256, 0, stream>>>(ei);
    k_mfin<H><<<NH, 256, 0, stream>>>();
    k_esum<H><<<EB, 256, 0, stream>>>(ei);
    k_gather<H, O, C, LEAKY><<<GB, 256, 0, stream>>>(bias, s_b);
}

// ---------------- launch ----------------
extern "C" void kernel_launch(void* const* d_in, const int* in_sizes, int n_in,
                              void* d_out, int out_size, void* d_ws, size_t ws_size,
                              hipStream_t stream){
    static const int want[20] = {300000, 6400, 1600000, 50000,
                                 774, 129, 129, 129,
                                 16641, 129, 129, 129,
                                 16512, 128, 128, 128,
                                 512, 256, 32768, 128};
    const void* P[20];
    bool assigned[20];
    for (int s = 0; s < 20; s++){ P[s] = nullptr; assigned[s] = false; }
    bool ok = (n_in == 20);
    if (ok){
        for (int i = 0; i < 20; i++){
            int sz = in_sizes[i], hit = -1;
            for (int s = 0; s < 20; s++)
                if (!assigned[s] && want[s] == sz){ hit = s; break; }
            if (hit < 0){ ok = false; break; }
            P[hit] = d_in[i]; assigned[hit] = true;
        }
        for (int s = 0; s < 20 && ok; s++) if (!assigned[s]) ok = false;
    }
    if (!ok) for (int s = 0; s < 20 && s < n_in; s++) P[s] = d_in[s];

    const void* x    = P[0];
    const void* loc  = P[1];
    const void* ei   = P[2];
    const void* batch= P[3];
    const void* W0   = P[4];
    const void* as0  = P[5];
    const void* ad0  = P[6];
    const void* b0   = P[7];
    const void* W1   = P[8];
    const void* as1  = P[9];
    const void* ad1  = P[10];
    const void* b1   = P[11];
    const void* W2   = P[12];
    const void* as2  = P[13];
    const void* ad2  = P[14];
    const void* b2   = P[15];
    const void* Wl1  = P[16];
    const void* bl1  = P[17];
    const void* Wl2  = P[18];
    const void* bl2  = P[19];
    float* out = (float*)d_out;
    (void)d_ws; (void)ws_size; (void)out_size;

    const int EB = (E_TOT + 255) / 256;
    const int GEMM_B = (N_NODES + 7) / 8;
    k_detect<<<1, 64, 0, stream>>>(x, loc, W0, as0, ad0, W1, as1, ad1, W2, as2, ad2, Wl1, Wl2, ei);
    k_zero_global<<<(N_NODES + 255) / 256, 256, 0, stream>>>();

    // CSR build (graph shared by all 3 layers) — parallel 3-stage scan
    k_deg    <<<EB, 256, 0, stream>>>(ei);
    k_scan1  <<<SCAN_B, 256, 0, stream>>>();
    k_scan2  <<<1, 64, 0, stream>>>();
    k_scan3  <<<SCAN_B, 256, 0, stream>>>();
    k_fillcsr<<<EB, 256, 0, stream>>>(ei);

    // layer 0
    k_gemm0<<<(N_NODES * 129 + 255) / 256, 256, 0, stream>>>(x, W0);
    gat_layer<3, 43, 129, true>(ei, as0, ad0, b0, 5, 6, 7, stream);

    // layer 1
    k_prepW<129, 129><<<(129 * 132 + 255) / 256, 256, 0, stream>>>(W1, 8);
    k_gemmf<129, 129><<<GEMM_B, 256, 0, stream>>>();
    gat_layer<3, 43, 129, true>(ei, as1, ad1, b1, 9, 10, 11, stream);

    // layer 2
    k_prepW<129, 128><<<(129 * 132 + 255) / 256, 256, 0, stream>>>(W2, 12);
    k_gemmf<129, 128><<<GEMM_B, 256, 0, stream>>>();
    gat_layer<1, 128, 128, false>(ei, as2, ad2, b2, 13, 14, 15, stream);

    // pooling + output (f32 stores)
    k_poolA<<<(N_NODES + 127) / 128, 128, 0, stream>>>(batch);
    k_cnt  <<<1, 64, 0, stream>>>(batch);
    k_fin  <<<(N_GRAPHS * 128 + 255) / 256, 256, 0, stream>>>(out);
    k_loc  <<<N_GRAPHS, 256, 0, stream>>>(loc, Wl1, bl1, Wl2, bl2, out);
}

// Round 20
// 984.102 us; speedup vs baseline: 6.3314x; 1.6200x over previous
//
#include <hip/hip_runtime.h>
#include <hip/hip_bf16.h>
#include <math.h>

#define N_NODES  50000
#define N_EDGES  800000
#define E_TOT    850000   /* edges + self loops */
#define N_GRAPHS 64
#define N_LOCS   50
#define SCAN_B   ((N_NODES + 255) / 256)   /* 196 scan blocks */

typedef __hip_bfloat16 bf16;

// ---------------- static scratch ----------------
__device__ int      g_dt[20];                    // float inputs: 0=bf16, 1=f32, 2=f64
__device__ int      g_iw;                        // int inputs: 1 = int64, 0 = int32
__device__ int      g_deg[N_NODES];
__device__ int      g_cursor[N_NODES];
__device__ int      g_rowptr[N_NODES + 1];
__device__ int      g_bsum[SCAN_B];
__device__ int      g_csrc[E_TOT];               // CSR: src node per slot
__device__ int      g_cedge[E_TOT];              // CSR: edge id per slot (alpha index)
__device__ float    g_Wp[129 * 132];             // padded f32 weight for current layer
__device__ float    g_T[(size_t)N_NODES * 129];  // transformed features (this layer)
__device__ float    g_H[(size_t)N_NODES * 129];  // layer output (next layer input)
__device__ float    g_es[N_NODES * 3];
__device__ float    g_ed[N_NODES * 3];
__device__ float    g_z[N_NODES * 3];            // exp-sum
__device__ float    g_alpha[(size_t)E_TOT * 3];  // unnormalized exp weights per edge/head
__device__ float    g_gsum[N_GRAPHS * 128];
__device__ float    g_gcnt[N_GRAPHS];

// ---------------- helpers ----------------
__device__ __forceinline__ float b2f(bf16 x){ return __bfloat162float(x); }
__device__ __forceinline__ float lrelu(float x){ return x > 0.f ? x : 0.2f * x; }
__device__ __forceinline__ int   clampi(int v, int lo, int hi){ return v < lo ? lo : (v > hi ? hi : v); }
__device__ __forceinline__ float finz(float v){
    unsigned u = __float_as_uint(v);
    return ((u & 0x7F800000u) == 0x7F800000u) ? 0.f : v;   // NaN/inf -> 0
}
// dtype-dispatching sanitized float input load: 0=bf16, 1=f32, 2=f64
__device__ __forceinline__ float ldin(const void* p, int m, size_t i){
    float v = (m == 2) ? (float)((const double*)p)[i]
            : (m == 1) ? ((const float*)p)[i]
            :            b2f(((const bf16*)p)[i]);
    return finz(v);
}
__device__ __forceinline__ int ldi(const void* p, int wide, size_t i){
    return wide ? (int)((const long long*)p)[i] : ((const int*)p)[i];
}
__device__ __forceinline__ float expc(float a){ return __expf(fminf(fmaxf(a, -80.f), 0.f)); }
// edge -> (src,dst) including self-loops
__device__ __forceinline__ void edge_sd(const void* ei, int wide, int e, int& src, int& dst){
    if (e < N_EDGES){
        src = clampi(ldi(ei, wide, e), 0, N_NODES - 1);
        dst = clampi(ldi(ei, wide, (size_t)N_EDGES + e), 0, N_NODES - 1);
    } else {
        src = dst = e - N_EDGES;
    }
}

// ---------------- dtype detection (1 wave) ----------------
__global__ void k_detect(const void* x, const void* loc, const void* W0,
                         const void* as0, const void* ad0, const void* W1,
                         const void* as1, const void* ad1, const void* W2,
                         const void* as2, const void* ad2, const void* Wl1,
                         const void* Wl2, const void* ei){
    const void* ps[13] = {x, loc, W0, as0, ad0, W1, as1, ad1, W2, as2, ad2, Wl1, Wl2};
    const int  sl[13]  = {0,  1,   4,  5,   6,   8,  9,   10,  12, 13,  14,  16,  18};
    int lane = threadIdx.x;   // 64 lanes
    for (int t = 0; t < 13; t++){
        float vf = ((const float*)ps[t])[lane];
        unsigned uf = __float_as_uint(vf);
        bool hit64 = ((uf & 0x7F800000u) == 0x7F800000u) || fabsf(vf) > 1e4f;
        int n64 = __popcll(__ballot(hit64));

        float vb = b2f(((const bf16*)ps[t])[lane]);
        unsigned ub = __float_as_uint(vb);
        bool hit32 = ((ub & 0x7F800000u) == 0x7F800000u) || fabsf(vb) > 1e4f;
        int n32 = __popcll(__ballot(hit32));

        if (lane == 0) g_dt[sl[t]] = (n64 >= 2) ? 2 : ((n32 >= 2) ? 1 : 0);
    }
    int w0 = ((const int*)ei)[lane];
    unsigned long long zm = __ballot((lane & 1) && (w0 == 0));
    if (lane == 0){
        g_iw = (__popcll(zm) >= 16) ? 1 : 0;
        g_dt[2] = g_dt[3] = 0;
        g_dt[7] = g_dt[11] = g_dt[15] = 0;
        g_dt[17] = g_dt[19] = 0;
    }
}

// ---------------- zero init ----------------
__global__ void k_zero_global(){
    int i = blockIdx.x * blockDim.x + threadIdx.x;
    if (i < N_NODES) g_deg[i] = 0;
    if (i < N_GRAPHS * 128) g_gsum[i] = 0.f;
}

// ---------------- CSR build (once per call) ----------------
__global__ void k_deg(const void* __restrict__ ei){
    int wide = g_iw;
    int e = blockIdx.x * blockDim.x + threadIdx.x;
    if (e >= E_TOT) return;
    int src, dst; edge_sd(ei, wide, e, src, dst);
    atomicAdd(&g_deg[dst], 1);
}

// 3-stage parallel exclusive scan of g_deg -> g_rowptr/g_cursor
__global__ void k_scan1(){
    __shared__ int s[256];
    int i = blockIdx.x * 256 + threadIdx.x;
    int v = (i < N_NODES) ? g_deg[i] : 0;
    s[threadIdx.x] = v;
    __syncthreads();
    for (int off = 1; off < 256; off <<= 1){
        int add = (threadIdx.x >= off) ? s[threadIdx.x - off] : 0;
        __syncthreads();
        s[threadIdx.x] += add;
        __syncthreads();
    }
    if (threadIdx.x == 255) g_bsum[blockIdx.x] = s[255];
    if (i < N_NODES) g_rowptr[i] = s[threadIdx.x] - v;
}

__global__ void k_scan2(){
    int lane = threadIdx.x;
    int carry = 0;
    for (int base = 0; base < SCAN_B; base += 64){
        int i = base + lane;
        int v = (i < SCAN_B) ? g_bsum[i] : 0;
        int s = v;
        #pragma unroll
        for (int off = 1; off < 64; off <<= 1){
            int t = __shfl_up(s, off);
            if (lane >= off) s += t;
        }
        if (i < SCAN_B) g_bsum[i] = carry + s - v;
        carry += __shfl(s, 63);
    }
    if (lane == 0) g_rowptr[N_NODES] = carry;
}

__global__ void k_scan3(){
    int i = blockIdx.x * 256 + threadIdx.x;
    if (i < N_NODES){
        int r = g_rowptr[i] + g_bsum[blockIdx.x];
        g_rowptr[i] = r;
        g_cursor[i] = r;
    }
}

__global__ void k_fillcsr(const void* __restrict__ ei){
    int wide = g_iw;
    int e = blockIdx.x * blockDim.x + threadIdx.x;
    if (e >= E_TOT) return;
    int src, dst; edge_sd(ei, wide, e, src, dst);
    int pos = atomicAdd(&g_cursor[dst], 1);
    if (pos >= 0 && pos < E_TOT){ g_csrc[pos] = src; g_cedge[pos] = e; }
}

// ---------------- GEMMs ----------------
__global__ void k_gemm0(const void* __restrict__ x, const void* __restrict__ W){
    int dtx = g_dt[0], dtw = g_dt[4];
    int idx = blockIdx.x * blockDim.x + threadIdx.x;
    if (idx >= N_NODES * 129) return;
    int n = idx / 129, c = idx - n * 129;
    float acc = 0.f;
    #pragma unroll
    for (int k = 0; k < 6; k++)
        acc += ldin(x, dtx, (size_t)n * 6 + k) * ldin(W, dtw, k * 129 + c);
    g_T[idx] = finz(acc);
}

// pad/convert W [K][CO] -> g_Wp [K][132] (f32, sanitized) — once per layer
template<int K, int CO>
__global__ void k_prepW(const void* __restrict__ W, int slot){
    int m = g_dt[slot];
    int idx = blockIdx.x * blockDim.x + threadIdx.x;
    if (idx >= K * 132) return;
    int k = idx / 132, c = idx - k * 132;
    g_Wp[idx] = (c < CO) ? ldin(W, m, (size_t)k * CO + c) : 0.f;
}

// vectorized GEMM, 4 rows/thread: block = 32 rows x 32 col-groups
template<int K, int CO>
__global__ __launch_bounds__(256)
void k_gemmf(){
    int tid = threadIdx.x;
    int rg = tid >> 5;                  // 0..7
    int g  = tid & 31;
    int n0 = blockIdx.x * 32 + rg * 4;  // 4 consecutive rows per thread
    const float4* wp = (const float4*)g_Wp;   // [K][33] float4s
    float4 acc[4];
    float accE[4];
    const float* ar[4];
    #pragma unroll
    for (int r = 0; r < 4; r++){
        acc[r] = make_float4(0.f, 0.f, 0.f, 0.f);
        accE[r] = 0.f;
        int n = n0 + r;
        ar[r] = g_H + (size_t)(n < N_NODES ? n : N_NODES - 1) * K;
    }
    #pragma unroll 2
    for (int k = 0; k < K; k++){
        float4 w = wp[k * 33 + g];            // aligned 16B, L1-shared across block
        float we = (CO > 128 && g == 0) ? g_Wp[k * 132 + 128] : 0.f;
        #pragma unroll
        for (int r = 0; r < 4; r++){
            float a = ar[r][k];               // lane-uniform broadcast
            acc[r].x += a * w.x; acc[r].y += a * w.y;
            acc[r].z += a * w.z; acc[r].w += a * w.w;
            if (CO > 128 && g == 0) accE[r] += a * we;
        }
    }
    int c = 4 * g;
    #pragma unroll
    for (int r = 0; r < 4; r++){
        int n = n0 + r;
        if (n >= N_NODES) break;
        float* tr = g_T + (size_t)n * CO;
        tr[c] = acc[r].x; tr[c + 1] = acc[r].y; tr[c + 2] = acc[r].z; tr[c + 3] = acc[r].w;
        if (CO > 128 && g == 0) tr[128] = accE[r];
    }
}

// ---------------- per-node attention coefficients ----------------
template<int H, int O, int C>
__global__ void k_esed(const void* __restrict__ as, const void* __restrict__ ad,
                       int slot_as, int slot_ad){
    int dta = g_dt[slot_as], dtd = g_dt[slot_ad];
    int idx = blockIdx.x * blockDim.x + threadIdx.x;
    if (idx >= N_NODES * H) return;
    int n = idx / H, h = idx - n * H;
    const float* tr = g_T + (size_t)n * C + h * O;
    float a = 0.f, b = 0.f;
    #pragma unroll 4
    for (int o = 0; o < O; o++){
        float v = finz(tr[o]);
        a += v * ldin(as, dta, h * O + o);
        b += v * ldin(ad, dtd, h * O + o);
    }
    g_es[idx] = finz(a); g_ed[idx] = finz(b);
}

// ---------------- fused segment softmax (CSR, one wave per node) ------------
// Replaces zero_layer + emax + mfin + esum: computes per-node max and exp-sum
// in-wave (no atomics), writes alpha per edge and z per node exactly once.
template<int H>
__global__ __launch_bounds__(256)
void k_soft(){
    int wv = threadIdx.x >> 6, lane = threadIdx.x & 63;
    int n = blockIdx.x * 4 + wv;
    if (n >= N_NODES) return;
    int r0 = clampi(g_rowptr[n], 0, E_TOT);
    int r1 = clampi(g_rowptr[n + 1], r0, E_TOT);

    float edv[H], mx[H], se[H];
    #pragma unroll
    for (int h = 0; h < H; h++){ edv[h] = finz(g_ed[n * H + h]); mx[h] = -3.0e38f; se[h] = 0.f; }

    for (int i = r0 + lane; i < r1; i += 64){
        int s = clampi(g_csrc[i], 0, N_NODES - 1);
        #pragma unroll
        for (int h = 0; h < H; h++)
            mx[h] = fmaxf(mx[h], lrelu(finz(g_es[s * H + h]) + edv[h]));
    }
    #pragma unroll
    for (int h = 0; h < H; h++){
        for (int off = 32; off; off >>= 1) mx[h] = fmaxf(mx[h], __shfl_xor(mx[h], off));
        if (mx[h] < -1.0e38f) mx[h] = 0.f;   // empty segment (ref: non-finite -> 0)
    }
    for (int i = r0 + lane; i < r1; i += 64){
        int s = clampi(g_csrc[i], 0, N_NODES - 1);
        int e = clampi(g_cedge[i], 0, E_TOT - 1);
        #pragma unroll
        for (int h = 0; h < H; h++){
            float w = expc(lrelu(finz(g_es[s * H + h]) + edv[h]) - mx[h]);
            g_alpha[(size_t)e * H + h] = w;
            se[h] += w;
        }
    }
    #pragma unroll
    for (int h = 0; h < H; h++){
        for (int off = 32; off; off >>= 1) se[h] += __shfl_xor(se[h], off);
        if (lane == 0) g_z[n * H + h] = finz(se[h]);
    }
}

// ---------------- CSR gather: one wave per dst node, no atomics -------------
template<int H, int O, int C, bool LEAKY>
__global__ __launch_bounds__(256)
void k_gather(const void* __restrict__ bias, int slot_b){
    int dtb = g_dt[slot_b];
    int wv = threadIdx.x >> 6, lane = threadIdx.x & 63;
    int n = blockIdx.x * 4 + wv;
    if (n >= N_NODES) return;
    int r0 = clampi(g_rowptr[n], 0, E_TOT);
    int r1 = clampi(g_rowptr[n + 1], r0, E_TOT);

    float inv[H];
    #pragma unroll
    for (int h = 0; h < H; h++) inv[h] = 1.f / (finz(g_z[n * H + h]) + 1e-16f);

    const int h0 = lane / O;
    const int h1 = (lane + 64) / O;
    float iv0 = inv[h0], iv1 = inv[h1], ivL = inv[H - 1];
    float a0 = 0.f, a1 = 0.f, a2 = 0.f;
    for (int i = r0; i < r1; i++){
        int src = clampi(g_csrc[i], 0, N_NODES - 1);
        int e   = clampi(g_cedge[i], 0, E_TOT - 1);
        const float* tr = g_T + (size_t)src * C;
        float w0 = g_alpha[(size_t)e * H + h0] * iv0;
        float w1 = g_alpha[(size_t)e * H + h1] * iv1;
        a0 += finz(tr[lane]) * w0;
        a1 += finz(tr[lane + 64]) * w1;
        if (C > 128 && lane == 0)
            a2 += finz(tr[128]) * g_alpha[(size_t)e * H + H - 1] * ivL;
    }
    float o0 = finz(a0) + ldin(bias, dtb, lane);
    float o1 = finz(a1) + ldin(bias, dtb, lane + 64);
    if (LEAKY){ o0 = lrelu(o0); o1 = lrelu(o1); }
    g_H[(size_t)n * C + lane] = finz(o0);
    g_H[(size_t)n * C + lane + 64] = finz(o1);
    if (C > 128 && lane == 0){
        float o2 = finz(a2) + ldin(bias, dtb, 128);
        if (LEAKY) o2 = lrelu(o2);
        g_H[(size_t)n * C + 128] = finz(o2);
    }
}

// ---------------- pooling (batch is sorted by construction) ----------------
__global__ void k_poolA(const void* __restrict__ batch){
    int wide = g_iw;
    int c = threadIdx.x;              // 128 channels
    int n0 = blockIdx.x * 128;
    int bprev = -1; float acc = 0.f;
    for (int j = 0; j < 128; j++){
        int n = n0 + j;
        if (n >= N_NODES) break;
        int b = clampi(ldi(batch, wide, n), 0, N_GRAPHS - 1);
        if (b != bprev){
            if (bprev >= 0) atomicAdd(&g_gsum[bprev * 128 + c], acc);
            acc = 0.f; bprev = b;
        }
        acc += finz(g_H[(size_t)n * 128 + c]);
    }
    if (bprev >= 0) atomicAdd(&g_gsum[bprev * 128 + c], acc);
}

// per-graph node count via binary search on sorted batch (no atomics)
__global__ void k_cnt(const void* __restrict__ batch){
    int wide = g_iw;
    int b = threadIdx.x;              // 64 threads
    if (b >= N_GRAPHS) return;
    int lo = 0, hi = N_NODES;
    while (lo < hi){ int mid = (lo + hi) >> 1; if (ldi(batch, wide, mid) <  b) lo = mid + 1; else hi = mid; }
    int start = lo;
    lo = 0; hi = N_NODES;
    while (lo < hi){ int mid = (lo + hi) >> 1; if (ldi(batch, wide, mid) <= b) lo = mid + 1; else hi = mid; }
    g_gcnt[b] = (float)(lo - start);
}

// output is float32 (established r13/r14)
__global__ void k_fin(float* __restrict__ out){
    int idx = blockIdx.x * blockDim.x + threadIdx.x;
    if (idx >= N_GRAPHS * 128) return;
    int b = idx >> 7, c = idx & 127;
    out[b * 256 + c] = finz(finz(g_gsum[idx]) / fmaxf(g_gcnt[b], 1.f));
}

// ---------------- location-encoder MLP: fast two-stage (LDS) ----------------
__global__ void k_loc(const void* __restrict__ loc, const void* __restrict__ Wl1,
                      const void* __restrict__ bl1, const void* __restrict__ Wl2,
                      const void* __restrict__ bl2, float* __restrict__ out){
    int dtl = g_dt[1], dtw1 = g_dt[16], dtb1 = g_dt[17], dtw2 = g_dt[18], dtb2 = g_dt[19];
    int b = blockIdx.x, t = threadIdx.x;   // 64 blocks x 256 threads
    __shared__ float hs[256];
    float w0 = ldin(Wl1, dtw1, t);
    float w1 = ldin(Wl1, dtw1, 256 + t);
    float bb = ldin(bl1, dtb1, t);
    float s = 0.f;
    #pragma unroll 5
    for (int l = 0; l < N_LOCS; l++){
        float x0 = ldin(loc, dtl, ((size_t)b * N_LOCS + l) * 2);
        float x1 = ldin(loc, dtl, ((size_t)b * N_LOCS + l) * 2 + 1);
        s += tanhf(x0 * w0 + x1 * w1 + bb);
    }
    hs[t] = s;
    __syncthreads();
    if (t < 128){
        float acc = 0.f;
        #pragma unroll 8
        for (int j = 0; j < 256; j++) acc += hs[j] * ldin(Wl2, dtw2, (size_t)j * 128 + t);
        out[(size_t)b * 256 + 128 + t] = finz(acc * (1.f / (float)N_LOCS) + ldin(bl2, dtb2, t));
    }
}

// ---------------- per-layer driver ----------------
template<int H, int O, int C, bool LEAKY>
static void gat_layer(const void* as, const void* ad, const void* bias,
                      int s_as, int s_ad, int s_b, hipStream_t stream){
    const int NH  = (N_NODES * H + 255) / 256;
    const int GB  = (N_NODES + 3) / 4;          // one wave per node
    k_esed<H, O, C><<<NH, 256, 0, stream>>>(as, ad, s_as, s_ad);
    k_soft<H><<<GB, 256, 0, stream>>>();
    k_gather<H, O, C, LEAKY><<<GB, 256, 0, stream>>>(bias, s_b);
}

// ---------------- launch ----------------
extern "C" void kernel_launch(void* const* d_in, const int* in_sizes, int n_in,
                              void* d_out, int out_size, void* d_ws, size_t ws_size,
                              hipStream_t stream){
    static const int want[20] = {300000, 6400, 1600000, 50000,
                                 774, 129, 129, 129,
                                 16641, 129, 129, 129,
                                 16512, 128, 128, 128,
                                 512, 256, 32768, 128};
    const void* P[20];
    bool assigned[20];
    for (int s = 0; s < 20; s++){ P[s] = nullptr; assigned[s] = false; }
    bool ok = (n_in == 20);
    if (ok){
        for (int i = 0; i < 20; i++){
            int sz = in_sizes[i], hit = -1;
            for (int s = 0; s < 20; s++)
                if (!assigned[s] && want[s] == sz){ hit = s; break; }
            if (hit < 0){ ok = false; break; }
            P[hit] = d_in[i]; assigned[hit] = true;
        }
        for (int s = 0; s < 20 && ok; s++) if (!assigned[s]) ok = false;
    }
    if (!ok) for (int s = 0; s < 20 && s < n_in; s++) P[s] = d_in[s];

    const void* x    = P[0];
    const void* loc  = P[1];
    const void* ei   = P[2];
    const void* batch= P[3];
    const void* W0   = P[4];
    const void* as0  = P[5];
    const void* ad0  = P[6];
    const void* b0   = P[7];
    const void* W1   = P[8];
    const void* as1  = P[9];
    const void* ad1  = P[10];
    const void* b1   = P[11];
    const void* W2   = P[12];
    const void* as2  = P[13];
    const void* ad2  = P[14];
    const void* b2   = P[15];
    const void* Wl1  = P[16];
    const void* bl1  = P[17];
    const void* Wl2  = P[18];
    const void* bl2  = P[19];
    float* out = (float*)d_out;
    (void)d_ws; (void)ws_size; (void)out_size;

    const int EB = (E_TOT + 255) / 256;
    const int GEMM_B = (N_NODES + 31) / 32;
    k_detect<<<1, 64, 0, stream>>>(x, loc, W0, as0, ad0, W1, as1, ad1, W2, as2, ad2, Wl1, Wl2, ei);
    k_zero_global<<<(N_NODES + 255) / 256, 256, 0, stream>>>();

    // CSR build (graph shared by all 3 layers) — parallel 3-stage scan
    k_deg    <<<EB, 256, 0, stream>>>(ei);
    k_scan1  <<<SCAN_B, 256, 0, stream>>>();
    k_scan2  <<<1, 64, 0, stream>>>();
    k_scan3  <<<SCAN_B, 256, 0, stream>>>();
    k_fillcsr<<<EB, 256, 0, stream>>>(ei);

    // layer 0
    k_gemm0<<<(N_NODES * 129 + 255) / 256, 256, 0, stream>>>(x, W0);
    gat_layer<3, 43, 129, true>(as0, ad0, b0, 5, 6, 7, stream);

    // layer 1
    k_prepW<129, 129><<<(129 * 132 + 255) / 256, 256, 0, stream>>>(W1, 8);
    k_gemmf<129, 129><<<GEMM_B, 256, 0, stream>>>();
    gat_layer<3, 43, 129, true>(as1, ad1, b1, 9, 10, 11, stream);

    // layer 2
    k_prepW<129, 128><<<(129 * 132 + 255) / 256, 256, 0, stream>>>(W2, 12);
    k_gemmf<129, 128><<<GEMM_B, 256, 0, stream>>>();
    gat_layer<1, 128, 128, false>(as2, ad2, b2, 13, 14, 15, stream);

    // pooling + output (f32 stores)
    k_poolA<<<(N_NODES + 127) / 128, 128, 0, stream>>>(batch);
    k_cnt  <<<1, 64, 0, stream>>>(batch);
    k_fin  <<<(N_GRAPHS * 128 + 255) / 256, 256, 0, stream>>>(out);
    k_loc  <<<N_GRAPHS, 256, 0, stream>>>(loc, Wl1, bl1, Wl2, bl2, out);
}

// Round 21
// 878.742 us; speedup vs baseline: 7.0905x; 1.1199x over previous
//
#include <hip/hip_runtime.h>
#include <hip/hip_bf16.h>
#include <math.h>

#define N_NODES  50000
#define N_EDGES  800000
#define E_TOT    850000   /* edges + self loops */
#define N_GRAPHS 64
#define N_LOCS   50
#define SCAN_B   ((N_NODES + 255) / 256)   /* 196 scan blocks */
#define TSTRIDE  130                       /* bf16 T row stride (4B-aligned) */

typedef __hip_bfloat16 bf16;

// ---------------- static scratch ----------------
__device__ int      g_dt[20];                    // float inputs: 0=bf16, 1=f32, 2=f64
__device__ int      g_iw;                        // int inputs: 1 = int64, 0 = int32
__device__ int      g_deg[N_NODES];
__device__ int      g_cursor[N_NODES];
__device__ int      g_rowptr[N_NODES + 1];
__device__ int      g_bsum[SCAN_B];
__device__ int      g_csrc[E_TOT];               // CSR: src node per slot
__device__ float    g_Wp[129 * 132];             // padded f32 weight for current layer
__device__ unsigned short g_Tb[(size_t)N_NODES * TSTRIDE];  // transformed features (bf16)
__device__ float    g_H[(size_t)N_NODES * 129];  // layer output (f32)
__device__ float    g_es[N_NODES * 3];
__device__ float    g_ed[N_NODES * 3];
__device__ float    g_gsum[N_GRAPHS * 128];
__device__ float    g_gcnt[N_GRAPHS];

// ---------------- helpers ----------------
__device__ __forceinline__ float b2f(bf16 x){ return __bfloat162float(x); }
__device__ __forceinline__ float lrelu(float x){ return x > 0.f ? x : 0.2f * x; }
__device__ __forceinline__ int   clampi(int v, int lo, int hi){ return v < lo ? lo : (v > hi ? hi : v); }
__device__ __forceinline__ float finz(float v){
    unsigned u = __float_as_uint(v);
    return ((u & 0x7F800000u) == 0x7F800000u) ? 0.f : v;   // NaN/inf -> 0
}
__device__ __forceinline__ unsigned short f2bu(float x){
    union { bf16 b; unsigned short u; } cv; cv.b = __float2bfloat16(x); return cv.u;
}
__device__ __forceinline__ float bu2f(unsigned short u){ return __uint_as_float(((unsigned)u) << 16); }
// dtype-dispatching sanitized float input load: 0=bf16, 1=f32, 2=f64
__device__ __forceinline__ float ldin(const void* p, int m, size_t i){
    float v = (m == 2) ? (float)((const double*)p)[i]
            : (m == 1) ? ((const float*)p)[i]
            :            b2f(((const bf16*)p)[i]);
    return finz(v);
}
__device__ __forceinline__ int ldi(const void* p, int wide, size_t i){
    return wide ? (int)((const long long*)p)[i] : ((const int*)p)[i];
}
__device__ __forceinline__ float expc(float a){ return __expf(fminf(fmaxf(a, -80.f), 0.f)); }
// edge -> (src,dst) including self-loops
__device__ __forceinline__ void edge_sd(const void* ei, int wide, int e, int& src, int& dst){
    if (e < N_EDGES){
        src = clampi(ldi(ei, wide, e), 0, N_NODES - 1);
        dst = clampi(ldi(ei, wide, (size_t)N_EDGES + e), 0, N_NODES - 1);
    } else {
        src = dst = e - N_EDGES;
    }
}

// ---------------- dtype detection (1 wave) ----------------
__global__ void k_detect(const void* x, const void* loc, const void* W0,
                         const void* as0, const void* ad0, const void* W1,
                         const void* as1, const void* ad1, const void* W2,
                         const void* as2, const void* ad2, const void* Wl1,
                         const void* Wl2, const void* ei){
    const void* ps[13] = {x, loc, W0, as0, ad0, W1, as1, ad1, W2, as2, ad2, Wl1, Wl2};
    const int  sl[13]  = {0,  1,   4,  5,   6,   8,  9,   10,  12, 13,  14,  16,  18};
    int lane = threadIdx.x;   // 64 lanes
    for (int t = 0; t < 13; t++){
        float vf = ((const float*)ps[t])[lane];
        unsigned uf = __float_as_uint(vf);
        bool hit64 = ((uf & 0x7F800000u) == 0x7F800000u) || fabsf(vf) > 1e4f;
        int n64 = __popcll(__ballot(hit64));

        float vb = b2f(((const bf16*)ps[t])[lane]);
        unsigned ub = __float_as_uint(vb);
        bool hit32 = ((ub & 0x7F800000u) == 0x7F800000u) || fabsf(vb) > 1e4f;
        int n32 = __popcll(__ballot(hit32));

        if (lane == 0) g_dt[sl[t]] = (n64 >= 2) ? 2 : ((n32 >= 2) ? 1 : 0);
    }
    int w0 = ((const int*)ei)[lane];
    unsigned long long zm = __ballot((lane & 1) && (w0 == 0));
    if (lane == 0){
        g_iw = (__popcll(zm) >= 16) ? 1 : 0;
        g_dt[2] = g_dt[3] = 0;
        g_dt[7] = g_dt[11] = g_dt[15] = 0;
        g_dt[17] = g_dt[19] = 0;
    }
}

// ---------------- zero init ----------------
__global__ void k_zero_global(){
    int i = blockIdx.x * blockDim.x + threadIdx.x;
    if (i < N_NODES) g_deg[i] = 0;
    if (i < N_GRAPHS * 128) g_gsum[i] = 0.f;
}

// ---------------- CSR build (once per call) ----------------
__global__ void k_deg(const void* __restrict__ ei){
    int wide = g_iw;
    int e = blockIdx.x * blockDim.x + threadIdx.x;
    if (e >= E_TOT) return;
    int src, dst; edge_sd(ei, wide, e, src, dst);
    atomicAdd(&g_deg[dst], 1);
}

__global__ void k_scan1(){
    __shared__ int s[256];
    int i = blockIdx.x * 256 + threadIdx.x;
    int v = (i < N_NODES) ? g_deg[i] : 0;
    s[threadIdx.x] = v;
    __syncthreads();
    for (int off = 1; off < 256; off <<= 1){
        int add = (threadIdx.x >= off) ? s[threadIdx.x - off] : 0;
        __syncthreads();
        s[threadIdx.x] += add;
        __syncthreads();
    }
    if (threadIdx.x == 255) g_bsum[blockIdx.x] = s[255];
    if (i < N_NODES) g_rowptr[i] = s[threadIdx.x] - v;
}

__global__ void k_scan2(){
    int lane = threadIdx.x;
    int carry = 0;
    for (int base = 0; base < SCAN_B; base += 64){
        int i = base + lane;
        int v = (i < SCAN_B) ? g_bsum[i] : 0;
        int s = v;
        #pragma unroll
        for (int off = 1; off < 64; off <<= 1){
            int t = __shfl_up(s, off);
            if (lane >= off) s += t;
        }
        if (i < SCAN_B) g_bsum[i] = carry + s - v;
        carry += __shfl(s, 63);
    }
    if (lane == 0) g_rowptr[N_NODES] = carry;
}

__global__ void k_scan3(){
    int i = blockIdx.x * 256 + threadIdx.x;
    if (i < N_NODES){
        int r = g_rowptr[i] + g_bsum[blockIdx.x];
        g_rowptr[i] = r;
        g_cursor[i] = r;
    }
}

__global__ void k_fillcsr(const void* __restrict__ ei){
    int wide = g_iw;
    int e = blockIdx.x * blockDim.x + threadIdx.x;
    if (e >= E_TOT) return;
    int src, dst; edge_sd(ei, wide, e, src, dst);
    int pos = atomicAdd(&g_cursor[dst], 1);
    if (pos >= 0 && pos < E_TOT) g_csrc[pos] = src;
}

// ---------------- GEMMs (write bf16 T) ----------------
__global__ void k_gemm0(const void* __restrict__ x, const void* __restrict__ W){
    int dtx = g_dt[0], dtw = g_dt[4];
    int idx = blockIdx.x * blockDim.x + threadIdx.x;
    if (idx >= N_NODES * 129) return;
    int n = idx / 129, c = idx - n * 129;
    float acc = 0.f;
    #pragma unroll
    for (int k = 0; k < 6; k++)
        acc += ldin(x, dtx, (size_t)n * 6 + k) * ldin(W, dtw, k * 129 + c);
    g_Tb[(size_t)n * TSTRIDE + c] = f2bu(finz(acc));
}

// pad/convert W [K][CO] -> g_Wp [K][132] (f32, sanitized) — once per layer
template<int K, int CO>
__global__ void k_prepW(const void* __restrict__ W, int slot){
    int m = g_dt[slot];
    int idx = blockIdx.x * blockDim.x + threadIdx.x;
    if (idx >= K * 132) return;
    int k = idx / 132, c = idx - k * 132;
    g_Wp[idx] = (c < CO) ? ldin(W, m, (size_t)k * CO + c) : 0.f;
}

// vectorized GEMM, 4 rows/thread: block = 32 rows x 32 col-groups, bf16 out
template<int K, int CO>
__global__ __launch_bounds__(256)
void k_gemmf(){
    int tid = threadIdx.x;
    int rg = tid >> 5;                  // 0..7
    int g  = tid & 31;
    int n0 = blockIdx.x * 32 + rg * 4;  // 4 consecutive rows per thread
    const float4* wp = (const float4*)g_Wp;   // [K][33] float4s
    float4 acc[4];
    float accE[4];
    const float* ar[4];
    #pragma unroll
    for (int r = 0; r < 4; r++){
        acc[r] = make_float4(0.f, 0.f, 0.f, 0.f);
        accE[r] = 0.f;
        int n = n0 + r;
        ar[r] = g_H + (size_t)(n < N_NODES ? n : N_NODES - 1) * K;
    }
    #pragma unroll 2
    for (int k = 0; k < K; k++){
        float4 w = wp[k * 33 + g];
        float we = (CO > 128 && g == 0) ? g_Wp[k * 132 + 128] : 0.f;
        #pragma unroll
        for (int r = 0; r < 4; r++){
            float a = ar[r][k];
            acc[r].x += a * w.x; acc[r].y += a * w.y;
            acc[r].z += a * w.z; acc[r].w += a * w.w;
            if (CO > 128 && g == 0) accE[r] += a * we;
        }
    }
    #pragma unroll
    for (int r = 0; r < 4; r++){
        int n = n0 + r;
        if (n >= N_NODES) break;
        unsigned* tw = (unsigned*)(g_Tb + (size_t)n * TSTRIDE);
        tw[g * 2]     = ((unsigned)f2bu(acc[r].y) << 16) | f2bu(acc[r].x);
        tw[g * 2 + 1] = ((unsigned)f2bu(acc[r].w) << 16) | f2bu(acc[r].z);
        if (CO > 128 && g == 0) g_Tb[(size_t)n * TSTRIDE + 128] = f2bu(accE[r]);
    }
}

// ---------------- per-node attention coefficients (bf16 T reads) ------------
template<int H, int O, int C>
__global__ void k_esed(const void* __restrict__ as, const void* __restrict__ ad,
                       int slot_as, int slot_ad){
    int dta = g_dt[slot_as], dtd = g_dt[slot_ad];
    int idx = blockIdx.x * blockDim.x + threadIdx.x;
    if (idx >= N_NODES * H) return;
    int n = idx / H, h = idx - n * H;
    const unsigned short* tr = g_Tb + (size_t)n * TSTRIDE + h * O;
    float a = 0.f, b = 0.f;
    #pragma unroll 4
    for (int o = 0; o < O; o++){
        float v = bu2f(tr[o]);
        a += v * ldin(as, dta, h * O + o);
        b += v * ldin(ad, dtd, h * O + o);
    }
    g_es[idx] = finz(a); g_ed[idx] = finz(b);
}

// ------- FUSED segment-softmax + gather: one wave per dst node, no atomics ---
// pass1: per-node per-head max (lanes stride edges, shuffle-reduce).
// pass2: serial edges, lanes over channel-pairs (bf16x2 dword loads);
//        accumulates unnormalized sum and per-head z in-register (all lanes
//        sharing a head accumulate the identical w sequence == z).
template<int H, int O, int C, bool LEAKY>
__global__ __launch_bounds__(256)
void k_fgat(const void* __restrict__ bias, int slot_b){
    int dtb = g_dt[slot_b];
    int wv = threadIdx.x >> 6, lane = threadIdx.x & 63;
    int n = blockIdx.x * 4 + wv;
    if (n >= N_NODES) return;
    int r0 = clampi(g_rowptr[n], 0, E_TOT);
    int r1 = clampi(g_rowptr[n + 1], r0, E_TOT);

    float edv[H], mx[H];
    #pragma unroll
    for (int h = 0; h < H; h++){ edv[h] = finz(g_ed[n * H + h]); mx[h] = -3.0e38f; }

    for (int i = r0 + lane; i < r1; i += 64){
        int s = clampi(g_csrc[i], 0, N_NODES - 1);
        #pragma unroll
        for (int h = 0; h < H; h++)
            mx[h] = fmaxf(mx[h], lrelu(finz(g_es[s * H + h]) + edv[h]));
    }
    #pragma unroll
    for (int h = 0; h < H; h++){
        for (int off = 32; off; off >>= 1) mx[h] = fmaxf(mx[h], __shfl_xor(mx[h], off));
        if (mx[h] < -1.0e38f) mx[h] = 0.f;   // empty segment (ref: non-finite -> 0)
    }

    const int c0 = 2 * lane, c1 = 2 * lane + 1;
    const int h0 = c0 / O, h1 = c1 / O;
    float edA = edv[h0], mxA = mx[h0];
    float edB = edv[h1], mxB = mx[h1];
    float edL = edv[H - 1], mxL = mx[H - 1];
    float a0 = 0.f, a1 = 0.f, a2 = 0.f;
    float zA = 0.f, zB = 0.f, zL = 0.f;
    for (int i = r0; i < r1; i++){
        int s = clampi(g_csrc[i], 0, N_NODES - 1);
        const unsigned* tr = (const unsigned*)(g_Tb + (size_t)s * TSTRIDE);
        unsigned pv = tr[lane];
        float wA = expc(lrelu(finz(g_es[s * H + h0]) + edA) - mxA);
        float wB = expc(lrelu(finz(g_es[s * H + h1]) + edB) - mxB);
        a0 += wA * __uint_as_float(pv << 16);
        a1 += wB * __uint_as_float(pv & 0xFFFF0000u);
        zA += wA; zB += wB;
        if (C > 128 && lane == 0){
            float wL = expc(lrelu(finz(g_es[s * H + H - 1]) + edL) - mxL);
            a2 += wL * bu2f(g_Tb[(size_t)s * TSTRIDE + 128]);
            zL += wL;
        }
    }
    float o0 = finz(a0 / (zA + 1e-16f)) + ldin(bias, dtb, c0);
    float o1 = finz(a1 / (zB + 1e-16f)) + ldin(bias, dtb, c1);
    if (LEAKY){ o0 = lrelu(o0); o1 = lrelu(o1); }
    g_H[(size_t)n * C + c0] = finz(o0);
    g_H[(size_t)n * C + c1] = finz(o1);
    if (C > 128 && lane == 0){
        float o2 = finz(a2 / (zL + 1e-16f)) + ldin(bias, dtb, 128);
        if (LEAKY) o2 = lrelu(o2);
        g_H[(size_t)n * C + 128] = finz(o2);
    }
}

// ---------------- pooling (batch is sorted by construction) ----------------
__global__ void k_poolA(const void* __restrict__ batch){
    int wide = g_iw;
    int c = threadIdx.x;              // 128 channels
    int n0 = blockIdx.x * 128;
    int bprev = -1; float acc = 0.f;
    for (int j = 0; j < 128; j++){
        int n = n0 + j;
        if (n >= N_NODES) break;
        int b = clampi(ldi(batch, wide, n), 0, N_GRAPHS - 1);
        if (b != bprev){
            if (bprev >= 0) atomicAdd(&g_gsum[bprev * 128 + c], acc);
            acc = 0.f; bprev = b;
        }
        acc += finz(g_H[(size_t)n * 128 + c]);
    }
    if (bprev >= 0) atomicAdd(&g_gsum[bprev * 128 + c], acc);
}

// per-graph node count via binary search on sorted batch (no atomics)
__global__ void k_cnt(const void* __restrict__ batch){
    int wide = g_iw;
    int b = threadIdx.x;              // 64 threads
    if (b >= N_GRAPHS) return;
    int lo = 0, hi = N_NODES;
    while (lo < hi){ int mid = (lo + hi) >> 1; if (ldi(batch, wide, mid) <  b) lo = mid + 1; else hi = mid; }
    int start = lo;
    lo = 0; hi = N_NODES;
    while (lo < hi){ int mid = (lo + hi) >> 1; if (ldi(batch, wide, mid) <= b) lo = mid + 1; else hi = mid; }
    g_gcnt[b] = (float)(lo - start);
}

// output is float32 (established r13/r14)
__global__ void k_fin(float* __restrict__ out){
    int idx = blockIdx.x * blockDim.x + threadIdx.x;
    if (idx >= N_GRAPHS * 128) return;
    int b = idx >> 7, c = idx & 127;
    out[b * 256 + c] = finz(finz(g_gsum[idx]) / fmaxf(g_gcnt[b], 1.f));
}

// ---------------- location-encoder MLP: fast two-stage (LDS) ----------------
__global__ void k_loc(const void* __restrict__ loc, const void* __restrict__ Wl1,
                      const void* __restrict__ bl1, const void* __restrict__ Wl2,
                      const void* __restrict__ bl2, float* __restrict__ out){
    int dtl = g_dt[1], dtw1 = g_dt[16], dtb1 = g_dt[17], dtw2 = g_dt[18], dtb2 = g_dt[19];
    int b = blockIdx.x, t = threadIdx.x;   // 64 blocks x 256 threads
    __shared__ float hs[256];
    float w0 = ldin(Wl1, dtw1, t);
    float w1 = ldin(Wl1, dtw1, 256 + t);
    float bb = ldin(bl1, dtb1, t);
    float s = 0.f;
    #pragma unroll 5
    for (int l = 0; l < N_LOCS; l++){
        float x0 = ldin(loc, dtl, ((size_t)b * N_LOCS + l) * 2);
        float x1 = ldin(loc, dtl, ((size_t)b * N_LOCS + l) * 2 + 1);
        s += tanhf(x0 * w0 + x1 * w1 + bb);
    }
    hs[t] = s;
    __syncthreads();
    if (t < 128){
        float acc = 0.f;
        #pragma unroll 8
        for (int j = 0; j < 256; j++) acc += hs[j] * ldin(Wl2, dtw2, (size_t)j * 128 + t);
        out[(size_t)b * 256 + 128 + t] = finz(acc * (1.f / (float)N_LOCS) + ldin(bl2, dtb2, t));
    }
}

// ---------------- per-layer driver ----------------
template<int H, int O, int C, bool LEAKY>
static void gat_layer(const void* as, const void* ad, const void* bias,
                      int s_as, int s_ad, int s_b, hipStream_t stream){
    const int NH  = (N_NODES * H + 255) / 256;
    const int GB  = (N_NODES + 3) / 4;          // one wave per node
    k_esed<H, O, C><<<NH, 256, 0, stream>>>(as, ad, s_as, s_ad);
    k_fgat<H, O, C, LEAKY><<<GB, 256, 0, stream>>>(bias, s_b);
}

// ---------------- launch ----------------
extern "C" void kernel_launch(void* const* d_in, const int* in_sizes, int n_in,
                              void* d_out, int out_size, void* d_ws, size_t ws_size,
                              hipStream_t stream){
    static const int want[20] = {300000, 6400, 1600000, 50000,
                                 774, 129, 129, 129,
                                 16641, 129, 129, 129,
                                 16512, 128, 128, 128,
                                 512, 256, 32768, 128};
    const void* P[20];
    bool assigned[20];
    for (int s = 0; s < 20; s++){ P[s] = nullptr; assigned[s] = false; }
    bool ok = (n_in == 20);
    if (ok){
        for (int i = 0; i < 20; i++){
            int sz = in_sizes[i], hit = -1;
            for (int s = 0; s < 20; s++)
                if (!assigned[s] && want[s] == sz){ hit = s; break; }
            if (hit < 0){ ok = false; break; }
            P[hit] = d_in[i]; assigned[hit] = true;
        }
        for (int s = 0; s < 20 && ok; s++) if (!assigned[s]) ok = false;
    }
    if (!ok) for (int s = 0; s < 20 && s < n_in; s++) P[s] = d_in[s];

    const void* x    = P[0];
    const void* loc  = P[1];
    const void* ei   = P[2];
    const void* batch= P[3];
    const void* W0   = P[4];
    const void* as0  = P[5];
    const void* ad0  = P[6];
    const void* b0   = P[7];
    const void* W1   = P[8];
    const void* as1  = P[9];
    const void* ad1  = P[10];
    const void* b1   = P[11];
    const void* W2   = P[12];
    const void* as2  = P[13];
    const void* ad2  = P[14];
    const void* b2   = P[15];
    const void* Wl1  = P[16];
    const void* bl1  = P[17];
    const void* Wl2  = P[18];
    const void* bl2  = P[19];
    float* out = (float*)d_out;
    (void)d_ws; (void)ws_size; (void)out_size;

    const int EB = (E_TOT + 255) / 256;
    const int GEMM_B = (N_NODES + 31) / 32;
    k_detect<<<1, 64, 0, stream>>>(x, loc, W0, as0, ad0, W1, as1, ad1, W2, as2, ad2, Wl1, Wl2, ei);
    k_zero_global<<<(N_NODES + 255) / 256, 256, 0, stream>>>();

    // CSR build (graph shared by all 3 layers) — parallel 3-stage scan
    k_deg    <<<EB, 256, 0, stream>>>(ei);
    k_scan1  <<<SCAN_B, 256, 0, stream>>>();
    k_scan2  <<<1, 64, 0, stream>>>();
    k_scan3  <<<SCAN_B, 256, 0, stream>>>();
    k_fillcsr<<<EB, 256, 0, stream>>>(ei);

    // layer 0
    k_gemm0<<<(N_NODES * 129 + 255) / 256, 256, 0, stream>>>(x, W0);
    gat_layer<3, 43, 129, true>(as0, ad0, b0, 5, 6, 7, stream);

    // layer 1
    k_prepW<129, 129><<<(129 * 132 + 255) / 256, 256, 0, stream>>>(W1, 8);
    k_gemmf<129, 129><<<GEMM_B, 256, 0, stream>>>();
    gat_layer<3, 43, 129, true>(as1, ad1, b1, 9, 10, 11, stream);

    // layer 2
    k_prepW<129, 128><<<(129 * 132 + 255) / 256, 256, 0, stream>>>(W2, 12);
    k_gemmf<129, 128><<<GEMM_B, 256, 0, stream>>>();
    gat_layer<1, 128, 128, false>(as2, ad2, b2, 13, 14, 15, stream);

    // pooling + output (f32 stores)
    k_poolA<<<(N_NODES + 127) / 128, 128, 0, stream>>>(batch);
    k_cnt  <<<1, 64, 0, stream>>>(batch);
    k_fin  <<<(N_GRAPHS * 128 + 255) / 256, 256, 0, stream>>>(out);
    k_loc  <<<N_GRAPHS, 256, 0, stream>>>(loc, Wl1, bl1, Wl2, bl2, out);
}

// Round 22
// 775.530 us; speedup vs baseline: 8.0342x; 1.1331x over previous
//
#include <hip/hip_runtime.h>
#include <hip/hip_bf16.h>
#include <math.h>

#define N_NODES  50000
#define N_EDGES  800000
#define E_TOT    850000   /* edges + self loops */
#define N_GRAPHS 64
#define N_LOCS   50
#define SCAN_B   ((N_NODES + 255) / 256)   /* 196 scan blocks */
#define TSTRIDE  130                       /* bf16 T row stride (4B-aligned) */

typedef __hip_bfloat16 bf16;

// ---------------- static scratch ----------------
__device__ int      g_dt[20];                    // float inputs: 0=bf16, 1=f32, 2=f64
__device__ int      g_iw;                        // int inputs: 1 = int64, 0 = int32
__device__ int      g_deg[N_NODES];
__device__ int      g_cursor[N_NODES];
__device__ int      g_rowptr[N_NODES + 1];
__device__ int      g_bsum[SCAN_B];
__device__ int      g_csrc[E_TOT];               // CSR: src node per slot
__device__ float    g_Wp[129 * 132];             // padded f32 weight for current layer
__device__ unsigned short g_Tb[(size_t)N_NODES * TSTRIDE];  // transformed features (bf16)
__device__ float    g_H[(size_t)N_NODES * 129];  // layer output (f32)
__device__ float    g_es[N_NODES * 3];
__device__ float    g_ed[N_NODES * 3];
__device__ float    g_gsum[N_GRAPHS * 128];
__device__ float    g_gcnt[N_GRAPHS];

// ---------------- helpers ----------------
__device__ __forceinline__ float b2f(bf16 x){ return __bfloat162float(x); }
__device__ __forceinline__ float lrelu(float x){ return x > 0.f ? x : 0.2f * x; }
__device__ __forceinline__ int   clampi(int v, int lo, int hi){ return v < lo ? lo : (v > hi ? hi : v); }
__device__ __forceinline__ float finz(float v){
    unsigned u = __float_as_uint(v);
    return ((u & 0x7F800000u) == 0x7F800000u) ? 0.f : v;   // NaN/inf -> 0
}
__device__ __forceinline__ unsigned short f2bu(float x){
    union { bf16 b; unsigned short u; } cv; cv.b = __float2bfloat16(x); return cv.u;
}
__device__ __forceinline__ float bu2f(unsigned short u){ return __uint_as_float(((unsigned)u) << 16); }
// dtype-dispatching sanitized float input load: 0=bf16, 1=f32, 2=f64
__device__ __forceinline__ float ldin(const void* p, int m, size_t i){
    float v = (m == 2) ? (float)((const double*)p)[i]
            : (m == 1) ? ((const float*)p)[i]
            :            b2f(((const bf16*)p)[i]);
    return finz(v);
}
__device__ __forceinline__ int ldi(const void* p, int wide, size_t i){
    return wide ? (int)((const long long*)p)[i] : ((const int*)p)[i];
}
__device__ __forceinline__ float expc(float a){ return __expf(fminf(fmaxf(a, -80.f), 0.f)); }
// edge -> (src,dst) including self-loops
__device__ __forceinline__ void edge_sd(const void* ei, int wide, int e, int& src, int& dst){
    if (e < N_EDGES){
        src = clampi(ldi(ei, wide, e), 0, N_NODES - 1);
        dst = clampi(ldi(ei, wide, (size_t)N_EDGES + e), 0, N_NODES - 1);
    } else {
        src = dst = e - N_EDGES;
    }
}

// ---------------- dtype detection (1 wave) ----------------
__global__ void k_detect(const void* x, const void* loc, const void* W0,
                         const void* as0, const void* ad0, const void* W1,
                         const void* as1, const void* ad1, const void* W2,
                         const void* as2, const void* ad2, const void* Wl1,
                         const void* Wl2, const void* ei){
    const void* ps[13] = {x, loc, W0, as0, ad0, W1, as1, ad1, W2, as2, ad2, Wl1, Wl2};
    const int  sl[13]  = {0,  1,   4,  5,   6,   8,  9,   10,  12, 13,  14,  16,  18};
    int lane = threadIdx.x;   // 64 lanes
    for (int t = 0; t < 13; t++){
        float vf = ((const float*)ps[t])[lane];
        unsigned uf = __float_as_uint(vf);
        bool hit64 = ((uf & 0x7F800000u) == 0x7F800000u) || fabsf(vf) > 1e4f;
        int n64 = __popcll(__ballot(hit64));

        float vb = b2f(((const bf16*)ps[t])[lane]);
        unsigned ub = __float_as_uint(vb);
        bool hit32 = ((ub & 0x7F800000u) == 0x7F800000u) || fabsf(vb) > 1e4f;
        int n32 = __popcll(__ballot(hit32));

        if (lane == 0) g_dt[sl[t]] = (n64 >= 2) ? 2 : ((n32 >= 2) ? 1 : 0);
    }
    int w0 = ((const int*)ei)[lane];
    unsigned long long zm = __ballot((lane & 1) && (w0 == 0));
    if (lane == 0){
        g_iw = (__popcll(zm) >= 16) ? 1 : 0;
        g_dt[2] = g_dt[3] = 0;
        g_dt[7] = g_dt[11] = g_dt[15] = 0;
        g_dt[17] = g_dt[19] = 0;
    }
}

// ---------------- zero init ----------------
__global__ void k_zero_global(){
    int i = blockIdx.x * blockDim.x + threadIdx.x;
    if (i < N_NODES) g_deg[i] = 0;
    if (i < N_GRAPHS * 128) g_gsum[i] = 0.f;
}

// ---------------- CSR build (once per call) ----------------
__global__ void k_deg(const void* __restrict__ ei){
    int wide = g_iw;
    int e = blockIdx.x * blockDim.x + threadIdx.x;
    if (e >= E_TOT) return;
    int src, dst; edge_sd(ei, wide, e, src, dst);
    atomicAdd(&g_deg[dst], 1);
}

__global__ void k_scan1(){
    __shared__ int s[256];
    int i = blockIdx.x * 256 + threadIdx.x;
    int v = (i < N_NODES) ? g_deg[i] : 0;
    s[threadIdx.x] = v;
    __syncthreads();
    for (int off = 1; off < 256; off <<= 1){
        int add = (threadIdx.x >= off) ? s[threadIdx.x - off] : 0;
        __syncthreads();
        s[threadIdx.x] += add;
        __syncthreads();
    }
    if (threadIdx.x == 255) g_bsum[blockIdx.x] = s[255];
    if (i < N_NODES) g_rowptr[i] = s[threadIdx.x] - v;
}

__global__ void k_scan2(){
    int lane = threadIdx.x;
    int carry = 0;
    for (int base = 0; base < SCAN_B; base += 64){
        int i = base + lane;
        int v = (i < SCAN_B) ? g_bsum[i] : 0;
        int s = v;
        #pragma unroll
        for (int off = 1; off < 64; off <<= 1){
            int t = __shfl_up(s, off);
            if (lane >= off) s += t;
        }
        if (i < SCAN_B) g_bsum[i] = carry + s - v;
        carry += __shfl(s, 63);
    }
    if (lane == 0) g_rowptr[N_NODES] = carry;
}

__global__ void k_scan3(){
    int i = blockIdx.x * 256 + threadIdx.x;
    if (i < N_NODES){
        int r = g_rowptr[i] + g_bsum[blockIdx.x];
        g_rowptr[i] = r;
        g_cursor[i] = r;
    }
}

__global__ void k_fillcsr(const void* __restrict__ ei){
    int wide = g_iw;
    int e = blockIdx.x * blockDim.x + threadIdx.x;
    if (e >= E_TOT) return;
    int src, dst; edge_sd(ei, wide, e, src, dst);
    int pos = atomicAdd(&g_cursor[dst], 1);
    if (pos >= 0 && pos < E_TOT) g_csrc[pos] = src;
}

// ---------------- GEMMs (write bf16 T) ----------------
__global__ void k_gemm0(const void* __restrict__ x, const void* __restrict__ W){
    int dtx = g_dt[0], dtw = g_dt[4];
    int idx = blockIdx.x * blockDim.x + threadIdx.x;
    if (idx >= N_NODES * 129) return;
    int n = idx / 129, c = idx - n * 129;
    float acc = 0.f;
    #pragma unroll
    for (int k = 0; k < 6; k++)
        acc += ldin(x, dtx, (size_t)n * 6 + k) * ldin(W, dtw, k * 129 + c);
    g_Tb[(size_t)n * TSTRIDE + c] = f2bu(finz(acc));
}

// pad/convert W [K][CO] -> g_Wp [K][132] (f32, sanitized) — once per layer
template<int K, int CO>
__global__ void k_prepW(const void* __restrict__ W, int slot){
    int m = g_dt[slot];
    int idx = blockIdx.x * blockDim.x + threadIdx.x;
    if (idx >= K * 132) return;
    int k = idx / 132, c = idx - k * 132;
    g_Wp[idx] = (c < CO) ? ldin(W, m, (size_t)k * CO + c) : 0.f;
}

// vectorized GEMM, 4 rows/thread: block = 32 rows x 32 col-groups, bf16 out
template<int K, int CO>
__global__ __launch_bounds__(256)
void k_gemmf(){
    int tid = threadIdx.x;
    int rg = tid >> 5;                  // 0..7
    int g  = tid & 31;
    int n0 = blockIdx.x * 32 + rg * 4;  // 4 consecutive rows per thread
    const float4* wp = (const float4*)g_Wp;   // [K][33] float4s
    float4 acc[4];
    float accE[4];
    const float* ar[4];
    #pragma unroll
    for (int r = 0; r < 4; r++){
        acc[r] = make_float4(0.f, 0.f, 0.f, 0.f);
        accE[r] = 0.f;
        int n = n0 + r;
        ar[r] = g_H + (size_t)(n < N_NODES ? n : N_NODES - 1) * K;
    }
    #pragma unroll 2
    for (int k = 0; k < K; k++){
        float4 w = wp[k * 33 + g];
        float we = (CO > 128 && g == 0) ? g_Wp[k * 132 + 128] : 0.f;
        #pragma unroll
        for (int r = 0; r < 4; r++){
            float a = ar[r][k];
            acc[r].x += a * w.x; acc[r].y += a * w.y;
            acc[r].z += a * w.z; acc[r].w += a * w.w;
            if (CO > 128 && g == 0) accE[r] += a * we;
        }
    }
    #pragma unroll
    for (int r = 0; r < 4; r++){
        int n = n0 + r;
        if (n >= N_NODES) break;
        unsigned* tw = (unsigned*)(g_Tb + (size_t)n * TSTRIDE);
        tw[g * 2]     = ((unsigned)f2bu(acc[r].y) << 16) | f2bu(acc[r].x);
        tw[g * 2 + 1] = ((unsigned)f2bu(acc[r].w) << 16) | f2bu(acc[r].z);
        if (CO > 128 && g == 0) g_Tb[(size_t)n * TSTRIDE + 128] = f2bu(accE[r]);
    }
}

// ---------------- per-node attention coefficients (bf16 T reads) ------------
template<int H, int O, int C>
__global__ void k_esed(const void* __restrict__ as, const void* __restrict__ ad,
                       int slot_as, int slot_ad){
    int dta = g_dt[slot_as], dtd = g_dt[slot_ad];
    int idx = blockIdx.x * blockDim.x + threadIdx.x;
    if (idx >= N_NODES * H) return;
    int n = idx / H, h = idx - n * H;
    const unsigned short* tr = g_Tb + (size_t)n * TSTRIDE + h * O;
    float a = 0.f, b = 0.f;
    #pragma unroll 4
    for (int o = 0; o < O; o++){
        float v = bu2f(tr[o]);
        a += v * ldin(as, dta, h * O + o);
        b += v * ldin(ad, dtd, h * O + o);
    }
    g_es[idx] = finz(a); g_ed[idx] = finz(b);
}

// ------- FUSED softmax+gather, chunked cooperative weights ------------------
// pass1: per-node per-head max (lanes stride edges, shuffle-reduce).
// pass2: edges in chunks of CH=64/H. Phase A: lane l computes exp-weight for
//        edge l/H, head l%H (ONE exp per lane per chunk). Phase B: serial
//        edges; w and src fetched via __shfl from computing lanes. Weight
//        values and z accumulation order identical to the unfused version.
template<int H, int O, int C, bool LEAKY>
__global__ __launch_bounds__(256)
void k_fgat(const void* __restrict__ bias, int slot_b){
    const int CH = 64 / H;               // 21 for H=3, 64 for H=1
    int dtb = g_dt[slot_b];
    int wv = threadIdx.x >> 6, lane = threadIdx.x & 63;
    int n = blockIdx.x * 4 + wv;
    if (n >= N_NODES) return;
    int r0 = clampi(g_rowptr[n], 0, E_TOT);
    int r1 = clampi(g_rowptr[n + 1], r0, E_TOT);

    float edv[H], mx[H];
    #pragma unroll
    for (int h = 0; h < H; h++){ edv[h] = finz(g_ed[n * H + h]); mx[h] = -3.0e38f; }

    for (int i = r0 + lane; i < r1; i += 64){
        int s = clampi(g_csrc[i], 0, N_NODES - 1);
        #pragma unroll
        for (int h = 0; h < H; h++)
            mx[h] = fmaxf(mx[h], lrelu(finz(g_es[s * H + h]) + edv[h]));
    }
    #pragma unroll
    for (int h = 0; h < H; h++){
        for (int off = 32; off; off >>= 1) mx[h] = fmaxf(mx[h], __shfl_xor(mx[h], off));
        if (mx[h] < -1.0e38f) mx[h] = 0.f;   // empty segment (ref: non-finite -> 0)
    }

    const int c0 = 2 * lane, c1 = 2 * lane + 1;
    const int h0 = c0 / O, h1 = c1 / O;
    const int jmine = lane / H;          // my edge slot within chunk
    const int hmine = lane - jmine * H;  // my head
    const float edm = edv[hmine], mxm = mx[hmine];
    float a0 = 0.f, a1 = 0.f, a2 = 0.f;
    float zA = 0.f, zB = 0.f, zL = 0.f;
    for (int base = r0; base < r1; base += CH){
        int m = r1 - base; if (m > CH) m = CH;
        // phase A: cooperative weight computation (1 exp per lane)
        float w = 0.f; int sA = 0;
        if (jmine < m){
            sA = clampi(g_csrc[base + jmine], 0, N_NODES - 1);
            w = expc(lrelu(finz(g_es[sA * H + hmine]) + edm) - mxm);
        }
        // phase B: serial gather over chunk edges
        for (int t = 0; t < m; t++){
            int s    = __shfl(sA, t * H);
            float wA = __shfl(w, t * H + h0);
            float wB = __shfl(w, t * H + h1);
            float wL = __shfl(w, t * H + (H - 1));
            const unsigned* tr = (const unsigned*)(g_Tb + (size_t)s * TSTRIDE);
            unsigned pv = tr[lane];
            a0 += wA * __uint_as_float(pv << 16);
            a1 += wB * __uint_as_float(pv & 0xFFFF0000u);
            zA += wA; zB += wB;
            if (C > 128 && lane == 0){
                a2 += wL * bu2f(g_Tb[(size_t)s * TSTRIDE + 128]);
                zL += wL;
            }
        }
    }
    float o0 = finz(a0 / (zA + 1e-16f)) + ldin(bias, dtb, c0);
    float o1 = finz(a1 / (zB + 1e-16f)) + ldin(bias, dtb, c1);
    if (LEAKY){ o0 = lrelu(o0); o1 = lrelu(o1); }
    g_H[(size_t)n * C + c0] = finz(o0);
    g_H[(size_t)n * C + c1] = finz(o1);
    if (C > 128 && lane == 0){
        float o2 = finz(a2 / (zL + 1e-16f)) + ldin(bias, dtb, 128);
        if (LEAKY) o2 = lrelu(o2);
        g_H[(size_t)n * C + 128] = finz(o2);
    }
}

// ---------------- pooling (batch is sorted by construction) ----------------
__global__ void k_poolA(const void* __restrict__ batch){
    int wide = g_iw;
    int c = threadIdx.x;              // 128 channels
    int n0 = blockIdx.x * 128;
    int bprev = -1; float acc = 0.f;
    for (int j = 0; j < 128; j++){
        int n = n0 + j;
        if (n >= N_NODES) break;
        int b = clampi(ldi(batch, wide, n), 0, N_GRAPHS - 1);
        if (b != bprev){
            if (bprev >= 0) atomicAdd(&g_gsum[bprev * 128 + c], acc);
            acc = 0.f; bprev = b;
        }
        acc += finz(g_H[(size_t)n * 128 + c]);
    }
    if (bprev >= 0) atomicAdd(&g_gsum[bprev * 128 + c], acc);
}

// per-graph node count via binary search on sorted batch (no atomics)
__global__ void k_cnt(const void* __restrict__ batch){
    int wide = g_iw;
    int b = threadIdx.x;              // 64 threads
    if (b >= N_GRAPHS) return;
    int lo = 0, hi = N_NODES;
    while (lo < hi){ int mid = (lo + hi) >> 1; if (ldi(batch, wide, mid) <  b) lo = mid + 1; else hi = mid; }
    int start = lo;
    lo = 0; hi = N_NODES;
    while (lo < hi){ int mid = (lo + hi) >> 1; if (ldi(batch, wide, mid) <= b) lo = mid + 1; else hi = mid; }
    g_gcnt[b] = (float)(lo - start);
}

// output is float32 (established r13/r14)
__global__ void k_fin(float* __restrict__ out){
    int idx = blockIdx.x * blockDim.x + threadIdx.x;
    if (idx >= N_GRAPHS * 128) return;
    int b = idx >> 7, c = idx & 127;
    out[b * 256 + c] = finz(finz(g_gsum[idx]) / fmaxf(g_gcnt[b], 1.f));
}

// ---------------- location-encoder MLP: fast two-stage (LDS) ----------------
__global__ void k_loc(const void* __restrict__ loc, const void* __restrict__ Wl1,
                      const void* __restrict__ bl1, const void* __restrict__ Wl2,
                      const void* __restrict__ bl2, float* __restrict__ out){
    int dtl = g_dt[1], dtw1 = g_dt[16], dtb1 = g_dt[17], dtw2 = g_dt[18], dtb2 = g_dt[19];
    int b = blockIdx.x, t = threadIdx.x;   // 64 blocks x 256 threads
    __shared__ float hs[256];
    float w0 = ldin(Wl1, dtw1, t);
    float w1 = ldin(Wl1, dtw1, 256 + t);
    float bb = ldin(bl1, dtb1, t);
    float s = 0.f;
    #pragma unroll 5
    for (int l = 0; l < N_LOCS; l++){
        float x0 = ldin(loc, dtl, ((size_t)b * N_LOCS + l) * 2);
        float x1 = ldin(loc, dtl, ((size_t)b * N_LOCS + l) * 2 + 1);
        s += tanhf(x0 * w0 + x1 * w1 + bb);
    }
    hs[t] = s;
    __syncthreads();
    if (t < 128){
        float acc = 0.f;
        #pragma unroll 8
        for (int j = 0; j < 256; j++) acc += hs[j] * ldin(Wl2, dtw2, (size_t)j * 128 + t);
        out[(size_t)b * 256 + 128 + t] = finz(acc * (1.f / (float)N_LOCS) + ldin(bl2, dtb2, t));
    }
}

// ---------------- per-layer driver ----------------
template<int H, int O, int C, bool LEAKY>
static void gat_layer(const void* as, const void* ad, const void* bias,
                      int s_as, int s_ad, int s_b, hipStream_t stream){
    const int NH  = (N_NODES * H + 255) / 256;
    const int GB  = (N_NODES + 3) / 4;          // one wave per node
    k_esed<H, O, C><<<NH, 256, 0, stream>>>(as, ad, s_as, s_ad);
    k_fgat<H, O, C, LEAKY><<<GB, 256, 0, stream>>>(bias, s_b);
}

// ---------------- launch ----------------
extern "C" void kernel_launch(void* const* d_in, const int* in_sizes, int n_in,
                              void* d_out, int out_size, void* d_ws, size_t ws_size,
                              hipStream_t stream){
    static const int want[20] = {300000, 6400, 1600000, 50000,
                                 774, 129, 129, 129,
                                 16641, 129, 129, 129,
                                 16512, 128, 128, 128,
                                 512, 256, 32768, 128};
    const void* P[20];
    bool assigned[20];
    for (int s = 0; s < 20; s++){ P[s] = nullptr; assigned[s] = false; }
    bool ok = (n_in == 20);
    if (ok){
        for (int i = 0; i < 20; i++){
            int sz = in_sizes[i], hit = -1;
            for (int s = 0; s < 20; s++)
                if (!assigned[s] && want[s] == sz){ hit = s; break; }
            if (hit < 0){ ok = false; break; }
            P[hit] = d_in[i]; assigned[hit] = true;
        }
        for (int s = 0; s < 20 && ok; s++) if (!assigned[s]) ok = false;
    }
    if (!ok) for (int s = 0; s < 20 && s < n_in; s++) P[s] = d_in[s];

    const void* x    = P[0];
    const void* loc  = P[1];
    const void* ei   = P[2];
    const void* batch= P[3];
    const void* W0   = P[4];
    const void* as0  = P[5];
    const void* ad0  = P[6];
    const void* b0   = P[7];
    const void* W1   = P[8];
    const void* as1  = P[9];
    const void* ad1  = P[10];
    const void* b1   = P[11];
    const void* W2   = P[12];
    const void* as2  = P[13];
    const void* ad2  = P[14];
    const void* b2   = P[15];
    const void* Wl1  = P[16];
    const void* bl1  = P[17];
    const void* Wl2  = P[18];
    const void* bl2  = P[19];
    float* out = (float*)d_out;
    (void)d_ws; (void)ws_size; (void)out_size;

    const int EB = (E_TOT + 255) / 256;
    const int GEMM_B = (N_NODES + 31) / 32;
    k_detect<<<1, 64, 0, stream>>>(x, loc, W0, as0, ad0, W1, as1, ad1, W2, as2, ad2, Wl1, Wl2, ei);
    k_zero_global<<<(N_NODES + 255) / 256, 256, 0, stream>>>();

    // CSR build (graph shared by all 3 layers) — parallel 3-stage scan
    k_deg    <<<EB, 256, 0, stream>>>(ei);
    k_scan1  <<<SCAN_B, 256, 0, stream>>>();
    k_scan2  <<<1, 64, 0, stream>>>();
    k_scan3  <<<SCAN_B, 256, 0, stream>>>();
    k_fillcsr<<<EB, 256, 0, stream>>>(ei);

    // layer 0
    k_gemm0<<<(N_NODES * 129 + 255) / 256, 256, 0, stream>>>(x, W0);
    gat_layer<3, 43, 129, true>(as0, ad0, b0, 5, 6, 7, stream);

    // layer 1
    k_prepW<129, 129><<<(129 * 132 + 255) / 256, 256, 0, stream>>>(W1, 8);
    k_gemmf<129, 129><<<GEMM_B, 256, 0, stream>>>();
    gat_layer<3, 43, 129, true>(as1, ad1, b1, 9, 10, 11, stream);

    // layer 2
    k_prepW<129, 128><<<(129 * 132 + 255) / 256, 256, 0, stream>>>(W2, 12);
    k_gemmf<129, 128><<<GEMM_B, 256, 0, stream>>>();
    gat_layer<1, 128, 128, false>(as2, ad2, b2, 13, 14, 15, stream);

    // pooling + output (f32 stores)
    k_poolA<<<(N_NODES + 127) / 128, 128, 0, stream>>>(batch);
    k_cnt  <<<1, 64, 0, stream>>>(batch);
    k_fin  <<<(N_GRAPHS * 128 + 255) / 256, 256, 0, stream>>>(out);
    k_loc  <<<N_GRAPHS, 256, 0, stream>>>(loc, Wl1, bl1, Wl2, bl2, out);
}